// Round 3
// baseline (745.136 us; speedup 1.0000x reference)
//
#include <hip/hip_runtime.h>
#include <cmath>

#define NN   512
#define SEQL 64
#define DIN  128
#define NH   4
#define NE   4096
#define DOUTN 128

__device__ __forceinline__ float lrelu(float v) { return v >= 0.f ? v : 0.2f * v; }

// ---------------- preprocess: x[N][S][D] -> H[S][N][D], keep ch0, log10(rest+1), NaN->0
__global__ __launch_bounds__(256) void preprocess_k(const float* __restrict__ x, float* __restrict__ H) {
    int idx = blockIdx.x * 256 + threadIdx.x;   // over N*S*D = 4,194,304
    int d = idx & 127;
    int s = (idx >> 7) & 63;
    int n = idx >> 13;
    float v = x[idx];
    if (d != 0) v = log10f(v + 1.0f);
    if (v != v) v = 0.0f;
    H[((size_t)s * NN + n) * DIN + d] = v;
}

// ---------------- CSR build (graph static across seq; built once per launch)
__global__ void csr_init_k(int* counts, int* fill) {
    int t = threadIdx.x;
    counts[t] = 0; fill[t] = 0;
}
__global__ void csr_hist_k(const int* __restrict__ dst, int* counts) {
    int e = blockIdx.x * 256 + threadIdx.x;
    if (e < NE) atomicAdd(&counts[dst[e]], 1);
}
__global__ void csr_scan_k(const int* __restrict__ counts, int* row_ptr) {
    if (threadIdx.x == 0) {
        int acc = 0;
        for (int i = 0; i < NN; ++i) { row_ptr[i] = acc; acc += counts[i]; }
        row_ptr[NN] = acc;
    }
}
__global__ void csr_scatter_k(const int* __restrict__ dst, const int* __restrict__ row_ptr,
                              int* fill, int* eidx) {
    int e = blockIdx.x * 256 + threadIdx.x;
    if (e < NE) {
        int dn = dst[e];
        int pos = atomicAdd(&fill[dn], 1);
        eidx[row_ptr[dn] + pos] = e;
    }
}

// ---------------- tiled f32 GEMM: C[M,N] = A[M,K] @ W[K,N] + bias[N]
#define BM 64
#define BN 64
#define BK 16
__global__ __launch_bounds__(256) void gemm_bias_k(const float* __restrict__ A, const float* __restrict__ W,
                                                   const float* __restrict__ bias, float* __restrict__ C,
                                                   int M, int N, int K) {
    __shared__ float As[BM][BK + 1];
    __shared__ float Bs[BK][BN];
    int t = threadIdx.x;
    int tx = t & 15, ty = t >> 4;
    int m0 = blockIdx.y * BM, n0 = blockIdx.x * BN;
    float acc[4][4] = {};
    for (int k0 = 0; k0 < K; k0 += BK) {
#pragma unroll
        for (int i = 0; i < 4; ++i) {
            int idx = t + i * 256;
            int mi = idx >> 4, ki = idx & 15;
            As[mi][ki] = A[(size_t)(m0 + mi) * K + k0 + ki];
            int ni = idx & 63, kj = idx >> 6;
            Bs[kj][ni] = W[(size_t)(k0 + kj) * N + n0 + ni];
        }
        __syncthreads();
#pragma unroll
        for (int k = 0; k < BK; ++k) {
            float a[4], b[4];
#pragma unroll
            for (int i = 0; i < 4; ++i) a[i] = As[ty * 4 + i][k];
#pragma unroll
            for (int j = 0; j < 4; ++j) b[j] = Bs[k][tx * 4 + j];
#pragma unroll
            for (int i = 0; i < 4; ++i)
#pragma unroll
                for (int j = 0; j < 4; ++j) acc[i][j] += a[i] * b[j];
        }
        __syncthreads();
    }
#pragma unroll
    for (int i = 0; i < 4; ++i) {
        int m = m0 + ty * 4 + i;
#pragma unroll
        for (int j = 0; j < 4; ++j) {
            int n = n0 + tx * 4 + j;
            C[(size_t)m * N + n] = acc[i][j] + bias[n];
        }
    }
}

// ---------------- layer-1 edge logits: one wave per (s,e); 4 heads x 128
__global__ __launch_bounds__(256) void edge_logits1_k(const float* __restrict__ FS, const float* __restrict__ FD,
                                                      const int* __restrict__ src, const int* __restrict__ dst,
                                                      const float* __restrict__ attn, float* __restrict__ LOG) {
    int wave = threadIdx.x >> 6, lane = threadIdx.x & 63;
    int ge = blockIdx.x * 4 + wave;           // < SC*NE
    int s = ge >> 12, e = ge & (NE - 1);
    int sn = src[e], dn = dst[e];
    const float* fsrow = FS + ((size_t)s * NN + sn) * 512;
    const float* fdrow = FD + ((size_t)s * NN + dn) * 512;
#pragma unroll
    for (int h = 0; h < NH; ++h) {
        float acc = 0.f;
#pragma unroll
        for (int r = 0; r < 2; ++r) {
            int d = h * 128 + lane + r * 64;
            float v = lrelu(fsrow[d] + fdrow[d]);
            acc += attn[h * 128 + lane + r * 64] * v;
        }
        for (int o = 32; o > 0; o >>= 1) acc += __shfl_xor(acc, o);
        if (lane == 0) LOG[(size_t)ge * NH + h] = acc;
    }
}

// ---------------- layer-1 per-node softmax + aggregation: block per (s,n), wave = head
__global__ __launch_bounds__(256) void node_agg1_k(const float* __restrict__ FS, const float* __restrict__ LOG,
                                                   const int* __restrict__ src, const int* __restrict__ row_ptr,
                                                   const int* __restrict__ eidx, float* __restrict__ G1) {
    int b = blockIdx.x;                 // < SC*NN
    int s = b / NN, n = b % NN;
    int h = threadIdx.x >> 6, lane = threadIdx.x & 63;
    int e0 = row_ptr[n], e1 = row_ptr[n + 1];
    const float* logs = LOG + (size_t)s * NE * NH;
    float m = -INFINITY;
    for (int j = e0 + lane; j < e1; j += 64) m = fmaxf(m, logs[eidx[j] * NH + h]);
    for (int o = 32; o > 0; o >>= 1) m = fmaxf(m, __shfl_xor(m, o));
    float den = 0.f;
    for (int j = e0 + lane; j < e1; j += 64) den += expf(logs[eidx[j] * NH + h] - m);
    for (int o = 32; o > 0; o >>= 1) den += __shfl_xor(den, o);
    float inv = 1.f / den;
    float a0 = 0.f, a1 = 0.f;
    for (int j = e0; j < e1; ++j) {
        int e = eidx[j];
        float w = expf(logs[e * NH + h] - m) * inv;
        const float* fsrow = FS + ((size_t)s * NN + src[e]) * 512 + h * 128;
        a0 += w * fsrow[lane];
        a1 += w * fsrow[lane + 64];
    }
    float* outr = G1 + ((size_t)s * NN + n) * 512 + h * 128;
    outr[lane] = a0; outr[lane + 64] = a1;
}

// ---------------- layer-2 edge logits (1 head, 128)
__global__ __launch_bounds__(256) void edge_logits2_k(const float* __restrict__ FS, const float* __restrict__ FD,
                                                      const int* __restrict__ src, const int* __restrict__ dst,
                                                      const float* __restrict__ attn, float* __restrict__ LOG) {
    int wave = threadIdx.x >> 6, lane = threadIdx.x & 63;
    int ge = blockIdx.x * 4 + wave;
    int s = ge >> 12, e = ge & (NE - 1);
    const float* fsrow = FS + ((size_t)s * NN + src[e]) * 128;
    const float* fdrow = FD + ((size_t)s * NN + dst[e]) * 128;
    float acc = 0.f;
#pragma unroll
    for (int r = 0; r < 2; ++r) {
        int d = lane + r * 64;
        acc += attn[d] * lrelu(fsrow[d] + fdrow[d]);
    }
    for (int o = 32; o > 0; o >>= 1) acc += __shfl_xor(acc, o);
    if (lane == 0) LOG[ge] = acc;
}

// ---------------- layer-2 per-node softmax + aggregation: wave per (s,n)
__global__ __launch_bounds__(256) void node_agg2_k(const float* __restrict__ FS, const float* __restrict__ LOG,
                                                   const int* __restrict__ src, const int* __restrict__ row_ptr,
                                                   const int* __restrict__ eidx, float* __restrict__ G2) {
    int wave = threadIdx.x >> 6, lane = threadIdx.x & 63;
    int g = blockIdx.x * 4 + wave;      // < SC*NN
    int s = g / NN, n = g % NN;
    int e0 = row_ptr[n], e1 = row_ptr[n + 1];
    const float* logs = LOG + (size_t)s * NE;
    float m = -INFINITY;
    for (int j = e0 + lane; j < e1; j += 64) m = fmaxf(m, logs[eidx[j]]);
    for (int o = 32; o > 0; o >>= 1) m = fmaxf(m, __shfl_xor(m, o));
    float den = 0.f;
    for (int j = e0 + lane; j < e1; j += 64) den += expf(logs[eidx[j]] - m);
    for (int o = 32; o > 0; o >>= 1) den += __shfl_xor(den, o);
    float inv = 1.f / den;
    float a0 = 0.f, a1 = 0.f;
    for (int j = e0; j < e1; ++j) {
        int e = eidx[j];
        float w = expf(logs[e] - m) * inv;
        const float* fsrow = FS + ((size_t)s * NN + src[e]) * 128;
        a0 += w * fsrow[lane];
        a1 += w * fsrow[lane + 64];
    }
    float* outr = G2 + ((size_t)s * NN + n) * 128;
    outr[lane] = a0; outr[lane + 64] = a1;
}

// ---------------- final: residual + NaN-guard + LayerNorm + FC; block per (s_local, n), 128 thr
__global__ __launch_bounds__(128) void final_k(const float* __restrict__ H, const float* __restrict__ G2,
                                               const float* __restrict__ gamma, const float* __restrict__ beta,
                                               const float* __restrict__ Wfc, const float* __restrict__ bfc,
                                               float* __restrict__ out, int s0) {
    int b = blockIdx.x;                 // < SC*NN
    int sl = b / NN, n = b % NN;
    int sg = s0 + sl;
    int t = threadIdx.x;                // 128
    __shared__ float yn[DIN];
    __shared__ float red[4];
    float xp = H[((size_t)sg * NN + n) * DIN + t];
    float g  = G2[((size_t)sl * NN + n) * DIN + t];
    if (g != g) g = xp;
    float o = xp + g;
    float ssum = o, ssq = o * o;
    for (int off = 32; off > 0; off >>= 1) { ssum += __shfl_xor(ssum, off); ssq += __shfl_xor(ssq, off); }
    int wave = t >> 6, lane = t & 63;
    if (lane == 0) { red[wave * 2] = ssum; red[wave * 2 + 1] = ssq; }
    __syncthreads();
    float S = red[0] + red[2], Q = red[1] + red[3];
    float mu = S * (1.f / 128.f);
    float var = Q * (1.f / 128.f) - mu * mu;
    float y = (o - mu) * rsqrtf(var + 1e-5f) * gamma[t] + beta[t];
    yn[t] = y;
    __syncthreads();
    float acc = bfc[t];
#pragma unroll 8
    for (int d = 0; d < DIN; ++d) acc += yn[d] * Wfc[d * DOUTN + t];
    out[((size_t)n * SEQL + sg) * DOUTN + t] = acc;
}

extern "C" void kernel_launch(void* const* d_in, const int* in_sizes, int n_in,
                              void* d_out, int out_size, void* d_ws, size_t ws_size,
                              hipStream_t stream) {
    const float* x     = (const float*)d_in[0];
    const int*   src   = (const int*)d_in[1];
    const int*   dst   = (const int*)d_in[2];
    const float* W1s   = (const float*)d_in[3];
    const float* b1s   = (const float*)d_in[4];
    const float* W1d   = (const float*)d_in[5];
    const float* b1d   = (const float*)d_in[6];
    const float* attn1 = (const float*)d_in[7];
    const float* W2s   = (const float*)d_in[8];
    const float* b2s   = (const float*)d_in[9];
    const float* W2d   = (const float*)d_in[10];
    const float* b2d   = (const float*)d_in[11];
    const float* attn2 = (const float*)d_in[12];
    const float* gamma = (const float*)d_in[13];
    const float* beta  = (const float*)d_in[14];
    const float* Wfc   = (const float*)d_in[15];
    const float* bfc   = (const float*)d_in[16];
    float* out = (float*)d_out;

    char* p = (char*)d_ws;
    float* H = (float*)p;                               // 64*512*128 f32 = 16,777,216 B
    int* counts  = (int*)(p + 16777216);                // 512
    int* row_ptr = counts + 512;                        // 513
    int* fill    = row_ptr + 513;                       // 512
    int* eidx    = fill + 512;                          // 4096
    size_t base = 16777216 + 32768;

    // pick largest seq-chunk that fits workspace: per-SC bytes = 3,473,408
    int SC = 1;
    const int cand[7] = {64, 32, 16, 8, 4, 2, 1};
    for (int i = 0; i < 7; ++i) {
        if (base + (size_t)cand[i] * 3473408ull <= ws_size) { SC = cand[i]; break; }
    }
    float* FS1  = (float*)(p + base);                   // SC*512*512
    float* FD1  = FS1  + (size_t)SC * 262144;           // SC*512*512
    float* G1   = FD1  + (size_t)SC * 262144;           // SC*512*512
    float* LOG1 = G1   + (size_t)SC * 262144;           // SC*4096*4
    float* G2   = LOG1 + (size_t)SC * 16384;            // SC*512*128
    // layer-2 aliases: FS2=FS1, FD2=FD1, LOG2=LOG1

    preprocess_k<<<(NN * SEQL * DIN) / 256, 256, 0, stream>>>(x, H);
    csr_init_k<<<1, 512, 0, stream>>>(counts, fill);
    csr_hist_k<<<NE / 256, 256, 0, stream>>>(dst, counts);
    csr_scan_k<<<1, 64, 0, stream>>>(counts, row_ptr);
    csr_scatter_k<<<NE / 256, 256, 0, stream>>>(dst, row_ptr, fill, eidx);

    for (int s0 = 0; s0 < SEQL; s0 += SC) {
        const float* Hc = H + (size_t)s0 * NN * DIN;
        int M = SC * NN;
        gemm_bias_k<<<dim3(512 / BN, M / BM), 256, 0, stream>>>(Hc, W1s, b1s, FS1, M, 512, 128);
        gemm_bias_k<<<dim3(512 / BN, M / BM), 256, 0, stream>>>(Hc, W1d, b1d, FD1, M, 512, 128);
        edge_logits1_k<<<SC * NE / 4, 256, 0, stream>>>(FS1, FD1, src, dst, attn1, LOG1);
        node_agg1_k<<<SC * NN, 256, 0, stream>>>(FS1, LOG1, src, row_ptr, eidx, G1);
        gemm_bias_k<<<dim3(128 / BN, M / BM), 256, 0, stream>>>(G1, W2s, b2s, FS1, M, 128, 512);
        gemm_bias_k<<<dim3(128 / BN, M / BM), 256, 0, stream>>>(G1, W2d, b2d, FD1, M, 128, 512);
        edge_logits2_k<<<SC * NE / 4, 256, 0, stream>>>(FS1, FD1, src, dst, attn2, LOG1);
        node_agg2_k<<<SC * NN / 4, 256, 0, stream>>>(FS1, LOG1, src, row_ptr, eidx, G2);
        final_k<<<SC * NN, 128, 0, stream>>>(H, G2, gamma, beta, Wfc, bfc, out, s0);
    }
}

// Round 4
// 368.947 us; speedup vs baseline: 2.0196x; 2.0196x over previous
//
#include <hip/hip_runtime.h>
#include <cmath>

#define NN    512
#define SEQL  64
#define DIN   128
#define NH    4
#define NE    4096
#define DOUTN 128

typedef __attribute__((ext_vector_type(4))) float f32x4;
typedef __attribute__((ext_vector_type(8))) short bf16x8;

__device__ __forceinline__ float lrelu(float v) { return v >= 0.f ? v : 0.2f * v; }

__device__ __forceinline__ unsigned short f2bf(float f) {
    union { float f; unsigned u; } x; x.f = f;
    unsigned r = (x.u + 0x7FFFu + ((x.u >> 16) & 1u)) >> 16;
    return (unsigned short)r;
}
__device__ __forceinline__ float bf2f(unsigned short h) {
    union { unsigned u; float f; } x; x.u = ((unsigned)h) << 16;
    return x.f;
}

// ---------------- preprocess: x[N][S][D] -> H f32 [S][N][D] + Hbf bf16 [S][N][D]
__global__ __launch_bounds__(256) void preprocess_k(const float* __restrict__ x,
                                                    float* __restrict__ H,
                                                    unsigned short* __restrict__ Hbf) {
    int tid = blockIdx.x * 256 + threadIdx.x;       // over 1,048,576 (4 elems each)
    int base = tid * 4;
    int d0 = base & 127;
    int s  = (base >> 7) & 63;
    int n  = base >> 13;
    float4 v = *(const float4*)(x + base);
    if (d0 == 0) {
        v.y = log10f(v.y + 1.f); v.z = log10f(v.z + 1.f); v.w = log10f(v.w + 1.f);
    } else {
        v.x = log10f(v.x + 1.f); v.y = log10f(v.y + 1.f);
        v.z = log10f(v.z + 1.f); v.w = log10f(v.w + 1.f);
    }
    if (v.x != v.x) v.x = 0.f;
    if (v.y != v.y) v.y = 0.f;
    if (v.z != v.z) v.z = 0.f;
    if (v.w != v.w) v.w = 0.f;
    size_t off = ((size_t)s * NN + n) * DIN + d0;
    *(float4*)(H + off) = v;
    ushort4 b; b.x = f2bf(v.x); b.y = f2bf(v.y); b.z = f2bf(v.z); b.w = f2bf(v.w);
    *(ushort4*)(Hbf + off) = b;
}

// ---------------- weight cast + transpose to [N][K] bf16
__global__ __launch_bounds__(256) void castw_k(const float* __restrict__ W1s, const float* __restrict__ W1d,
                                               const float* __restrict__ W2s, const float* __restrict__ W2d,
                                               const float* __restrict__ Wfc,
                                               unsigned short* __restrict__ T1s, unsigned short* __restrict__ T1d,
                                               unsigned short* __restrict__ T2s, unsigned short* __restrict__ T2d,
                                               unsigned short* __restrict__ Tfc) {
    int i = blockIdx.x * 256 + threadIdx.x;          // 278,528 total
    if (i < 65536) {                                  // T1s[512][128] <- W1s[128][512]
        int n = i >> 7, k = i & 127;
        T1s[i] = f2bf(W1s[k * 512 + n]);
    } else if (i < 131072) {
        int j = i - 65536; int n = j >> 7, k = j & 127;
        T1d[j] = f2bf(W1d[k * 512 + n]);
    } else if (i < 196608) {                          // T2s[128][512] <- W2s[512][128]
        int j = i - 131072; int n = j >> 9, k = j & 511;
        T2s[j] = f2bf(W2s[k * 128 + n]);
    } else if (i < 262144) {
        int j = i - 196608; int n = j >> 9, k = j & 511;
        T2d[j] = f2bf(W2d[k * 128 + n]);
    } else if (i < 278528) {                          // Tfc[128][128] <- Wfc[128][128]
        int j = i - 262144; int n = j >> 7, k = j & 127;
        Tfc[j] = f2bf(Wfc[k * 128 + n]);
    }
}

// ---------------- CSR build
__global__ void csr_init_k(int* counts, int* fill) {
    int t = threadIdx.x;
    counts[t] = 0; fill[t] = 0;
}
__global__ void csr_hist_k(const int* __restrict__ dst, int* counts) {
    int e = blockIdx.x * 256 + threadIdx.x;
    if (e < NE) atomicAdd(&counts[dst[e]], 1);
}
__global__ void csr_scan_k(const int* __restrict__ counts, int* __restrict__ row_ptr) {
    int l = threadIdx.x;                              // 64 lanes
    int c[8]; int lsum = 0;
#pragma unroll
    for (int j = 0; j < 8; ++j) { c[j] = counts[l * 8 + j]; lsum += c[j]; }
    int pre = lsum;
    for (int o = 1; o < 64; o <<= 1) {
        int v = __shfl_up(pre, o);
        if (l >= o) pre += v;
    }
    int acc = pre - lsum;                             // exclusive
#pragma unroll
    for (int j = 0; j < 8; ++j) { row_ptr[l * 8 + j] = acc; acc += c[j]; }
    if (l == 63) row_ptr[512] = acc;
}
__global__ void csr_scatter_k(const int* __restrict__ dst, const int* __restrict__ row_ptr,
                              int* fill, int* eidx) {
    int e = blockIdx.x * 256 + threadIdx.x;
    if (e < NE) {
        int dn = dst[e];
        int pos = atomicAdd(&fill[dn], 1);
        eidx[row_ptr[dn] + pos] = e;
    }
}

// ---------------- bf16 MFMA GEMM: C[M,N] = A[M,K]bf16 @ BT[N,K]bf16^T + bias
// 128x128 tile, BK=64, 256 thr (4 waves, 2x2), XOR-swizzled LDS, reg-staged.
template<int REMAP>
__global__ __launch_bounds__(256) void gemm_k(const unsigned short* __restrict__ A,
                                              const unsigned short* __restrict__ BT,
                                              const float* __restrict__ bias,
                                              void* __restrict__ C,
                                              int M, int N, int K, int s0) {
    __shared__ unsigned short As[8192];   // 128 rows x 64 cols (phys-swizzled), 16 KB
    __shared__ unsigned short Bs[8192];
    int t = threadIdx.x;
    int w = t >> 6, l = t & 63;
    int wr = w >> 1, wc = w & 1;
    int m0 = blockIdx.y * 128, n0 = blockIdx.x * 128;

    f32x4 acc[4][4];
#pragma unroll
    for (int i = 0; i < 4; ++i)
#pragma unroll
        for (int j = 0; j < 4; ++j) acc[i][j] = (f32x4){0.f, 0.f, 0.f, 0.f};

    for (int k0 = 0; k0 < K; k0 += 64) {
        bf16x8 ra[4], rb[4];
#pragma unroll
        for (int r = 0; r < 4; ++r) {
            int q = t * 16 + r * 4096;                 // logical byte in 16 KB tile
            int row = q >> 7;                          // 0..127
            int cole = (q & 127) >> 1;                 // element col 0..63 (8-aligned)
            ra[r] = *(const bf16x8*)(A  + (size_t)(m0 + row) * K + k0 + cole);
            rb[r] = *(const bf16x8*)(BT + (size_t)(n0 + row) * K + k0 + cole);
        }
        __syncthreads();                               // previous compute done
#pragma unroll
        for (int r = 0; r < 4; ++r) {
            int q = t * 16 + r * 4096;
            int row = q >> 7;
            int phys = (row << 7) | ((q & 127) ^ ((row & 7) << 4));
            *(bf16x8*)((char*)As + phys) = ra[r];
            *(bf16x8*)((char*)Bs + phys) = rb[r];
        }
        __syncthreads();
#pragma unroll
        for (int ks = 0; ks < 2; ++ks) {
            bf16x8 af[4], bfr[4];
#pragma unroll
            for (int i = 0; i < 4; ++i) {
                int row = wr * 64 + i * 16 + (l & 15);
                int colb = (ks * 64 + ((l >> 4) * 16)) ^ ((row & 7) << 4);
                af[i] = *(const bf16x8*)((const char*)As + (row << 7) + colb);
            }
#pragma unroll
            for (int j = 0; j < 4; ++j) {
                int row = wc * 64 + j * 16 + (l & 15);
                int colb = (ks * 64 + ((l >> 4) * 16)) ^ ((row & 7) << 4);
                bfr[j] = *(const bf16x8*)((const char*)Bs + (row << 7) + colb);
            }
#pragma unroll
            for (int i = 0; i < 4; ++i)
#pragma unroll
                for (int j = 0; j < 4; ++j)
                    acc[i][j] = __builtin_amdgcn_mfma_f32_16x16x32_bf16(af[i], bfr[j], acc[i][j], 0, 0, 0);
        }
    }

    float bl[4];
#pragma unroll
    for (int j = 0; j < 4; ++j) bl[j] = bias[n0 + wc * 64 + j * 16 + (l & 15)];
#pragma unroll
    for (int i = 0; i < 4; ++i) {
#pragma unroll
        for (int j = 0; j < 4; ++j) {
            int n = n0 + wc * 64 + j * 16 + (l & 15);
#pragma unroll
            for (int jj = 0; jj < 4; ++jj) {
                int m = m0 + wr * 64 + i * 16 + (l >> 4) * 4 + jj;
                float v = acc[i][j][jj] + bl[j];
                if (REMAP) {
                    int sl = m >> 9, node = m & 511;
                    ((float*)C)[((size_t)node * SEQL + (s0 + sl)) * DOUTN + n] = v;
                } else {
                    ((unsigned short*)C)[(size_t)m * N + n] = f2bf(v);
                }
            }
        }
    }
}

// ---------------- XCD-affine (s, idx) decode: B blocks per s, s%8 pinned to one XCD
__device__ __forceinline__ void s_swizzle(int bid, int sc, int B, int logB, int& s, int& idx) {
    if ((sc & 7) == 0) {
        int xcd = bid & 7;
        int j = bid >> 3;
        int grp = j >> logB;
        idx = j & (B - 1);
        s = grp * 8 + xcd;
    } else {
        s = bid >> logB;
        idx = bid & (B - 1);
    }
}

// ---------------- layer-1 edge logits: wave per (s,e); 4 heads x 128, bf16 in
__global__ __launch_bounds__(256) void edge_logits1_k(const unsigned short* __restrict__ FS,
                                                      const unsigned short* __restrict__ FD,
                                                      const int* __restrict__ src, const int* __restrict__ dst,
                                                      const float* __restrict__ attn, float* __restrict__ LOG,
                                                      int sc) {
    int w = threadIdx.x >> 6, l = threadIdx.x & 63;
    int s, eb;
    s_swizzle(blockIdx.x, sc, 1024, 10, s, eb);
    int e = eb * 4 + w;
    int sn = src[e], dn = dst[e];
    bf16x8 a = *(const bf16x8*)(FS + ((size_t)s * NN + sn) * 512 + l * 8);
    bf16x8 b = *(const bf16x8*)(FD + ((size_t)s * NN + dn) * 512 + l * 8);
    const float* at = attn + l * 8;
    float acc = 0.f;
#pragma unroll
    for (int j = 0; j < 8; ++j) {
        float v = bf2f((unsigned short)a[j]) + bf2f((unsigned short)b[j]);
        acc += at[j] * lrelu(v);
    }
#pragma unroll
    for (int o = 1; o < 16; o <<= 1) acc += __shfl_xor(acc, o);
    if ((l & 15) == 0) LOG[((size_t)s * NE + e) * 4 + (l >> 4)] = acc;
}

// ---------------- layer-1 softmax + aggregation: block per (s,n), wave = head
__global__ __launch_bounds__(256) void node_agg1_k(const unsigned short* __restrict__ FS,
                                                   const float* __restrict__ LOG,
                                                   const int* __restrict__ src, const int* __restrict__ row_ptr,
                                                   const int* __restrict__ eidx, unsigned short* __restrict__ G1,
                                                   int sc) {
    int s, n;
    s_swizzle(blockIdx.x, sc, 512, 9, s, n);
    int h = threadIdx.x >> 6, l = threadIdx.x & 63;
    int e0 = row_ptr[n], e1 = row_ptr[n + 1];
    const float* logs = LOG + (size_t)s * NE * 4;
    float m = -INFINITY;
    for (int j = e0 + l; j < e1; j += 64) m = fmaxf(m, logs[eidx[j] * 4 + h]);
    for (int o = 32; o > 0; o >>= 1) m = fmaxf(m, __shfl_xor(m, o));
    float den = 0.f;
    for (int j = e0 + l; j < e1; j += 64) den += expf(logs[eidx[j] * 4 + h] - m);
    for (int o = 32; o > 0; o >>= 1) den += __shfl_xor(den, o);
    float inv = 1.f / den;
    float a0 = 0.f, a1 = 0.f;
    for (int j = e0; j < e1; ++j) {
        int e = eidx[j];
        float wgt = expf(logs[e * 4 + h] - m) * inv;
        ushort2 uv = *(const ushort2*)(FS + ((size_t)s * NN + src[e]) * 512 + h * 128 + l * 2);
        a0 += wgt * bf2f(uv.x);
        a1 += wgt * bf2f(uv.y);
    }
    ushort2 o2; o2.x = f2bf(a0); o2.y = f2bf(a1);
    *(ushort2*)(G1 + ((size_t)s * NN + n) * 512 + h * 128 + l * 2) = o2;
}

// ---------------- layer-2 edge logits (1 head, 128), wave per (s,e)
__global__ __launch_bounds__(256) void edge_logits2_k(const unsigned short* __restrict__ FS,
                                                      const unsigned short* __restrict__ FD,
                                                      const int* __restrict__ src, const int* __restrict__ dst,
                                                      const float* __restrict__ attn, float* __restrict__ LOG,
                                                      int sc) {
    int w = threadIdx.x >> 6, l = threadIdx.x & 63;
    int s, eb;
    s_swizzle(blockIdx.x, sc, 1024, 10, s, eb);
    int e = eb * 4 + w;
    ushort2 ua = *(const ushort2*)(FS + ((size_t)s * NN + src[e]) * 128 + l * 2);
    ushort2 ub = *(const ushort2*)(FD + ((size_t)s * NN + dst[e]) * 128 + l * 2);
    float acc = attn[l * 2] * lrelu(bf2f(ua.x) + bf2f(ub.x))
              + attn[l * 2 + 1] * lrelu(bf2f(ua.y) + bf2f(ub.y));
    for (int o = 32; o > 0; o >>= 1) acc += __shfl_xor(acc, o);
    if (l == 0) LOG[(size_t)s * NE + e] = acc;
}

// ---------------- layer-2 softmax + aggregation: wave per (s,n)
__global__ __launch_bounds__(256) void node_agg2_k(const unsigned short* __restrict__ FS,
                                                   const float* __restrict__ LOG,
                                                   const int* __restrict__ src, const int* __restrict__ row_ptr,
                                                   const int* __restrict__ eidx, float* __restrict__ G2,
                                                   int sc) {
    int w = threadIdx.x >> 6, l = threadIdx.x & 63;
    int s, nb;
    s_swizzle(blockIdx.x, sc, 128, 7, s, nb);
    int n = nb * 4 + w;
    int e0 = row_ptr[n], e1 = row_ptr[n + 1];
    const float* logs = LOG + (size_t)s * NE;
    float m = -INFINITY;
    for (int j = e0 + l; j < e1; j += 64) m = fmaxf(m, logs[eidx[j]]);
    for (int o = 32; o > 0; o >>= 1) m = fmaxf(m, __shfl_xor(m, o));
    float den = 0.f;
    for (int j = e0 + l; j < e1; j += 64) den += expf(logs[eidx[j]] - m);
    for (int o = 32; o > 0; o >>= 1) den += __shfl_xor(den, o);
    float inv = 1.f / den;
    float a0 = 0.f, a1 = 0.f;
    for (int j = e0; j < e1; ++j) {
        int e = eidx[j];
        float wgt = expf(logs[e] - m) * inv;
        ushort2 uv = *(const ushort2*)(FS + ((size_t)s * NN + src[e]) * 128 + l * 2);
        a0 += wgt * bf2f(uv.x);
        a1 += wgt * bf2f(uv.y);
    }
    float2 o2; o2.x = a0; o2.y = a1;
    *(float2*)(G2 + ((size_t)s * NN + n) * 128 + l * 2) = o2;
}

// ---------------- residual + NaN-guard + LayerNorm -> bf16 Y
__global__ __launch_bounds__(128) void ln_k(const float* __restrict__ H, const float* __restrict__ G2,
                                            const float* __restrict__ gamma, const float* __restrict__ beta,
                                            unsigned short* __restrict__ Y, int s0) {
    int b = blockIdx.x;                 // sc*512
    int sl = b >> 9, n = b & 511;
    int t = threadIdx.x;                // 128
    __shared__ float red[4];
    float xp = H[((size_t)(s0 + sl) * NN + n) * DIN + t];
    float g  = G2[((size_t)sl * NN + n) * DIN + t];
    if (g != g) g = xp;
    float o = xp + g;
    float ssum = o, ssq = o * o;
    for (int off = 32; off > 0; off >>= 1) { ssum += __shfl_xor(ssum, off); ssq += __shfl_xor(ssq, off); }
    if ((t & 63) == 0) { red[(t >> 6) * 2] = ssum; red[(t >> 6) * 2 + 1] = ssq; }
    __syncthreads();
    float S = red[0] + red[2], Q = red[1] + red[3];
    float mu = S * (1.f / 128.f);
    float var = Q * (1.f / 128.f) - mu * mu;
    float y = (o - mu) * rsqrtf(var + 1e-5f) * gamma[t] + beta[t];
    Y[((size_t)sl * NN + n) * DIN + t] = f2bf(y);
}

extern "C" void kernel_launch(void* const* d_in, const int* in_sizes, int n_in,
                              void* d_out, int out_size, void* d_ws, size_t ws_size,
                              hipStream_t stream) {
    const float* x     = (const float*)d_in[0];
    const int*   src   = (const int*)d_in[1];
    const int*   dst   = (const int*)d_in[2];
    const float* W1s   = (const float*)d_in[3];
    const float* b1s   = (const float*)d_in[4];
    const float* W1d   = (const float*)d_in[5];
    const float* b1d   = (const float*)d_in[6];
    const float* attn1 = (const float*)d_in[7];
    const float* W2s   = (const float*)d_in[8];
    const float* b2s   = (const float*)d_in[9];
    const float* W2d   = (const float*)d_in[10];
    const float* b2d   = (const float*)d_in[11];
    const float* attn2 = (const float*)d_in[12];
    const float* gamma = (const float*)d_in[13];
    const float* beta  = (const float*)d_in[14];
    const float* Wfc   = (const float*)d_in[15];
    const float* bfc   = (const float*)d_in[16];
    float* out = (float*)d_out;

    char* p = (char*)d_ws;
    float*          H    = (float*)p;                          // 16,777,216 B
    unsigned short* Hbf  = (unsigned short*)(p + 16777216);    //  8,388,608 B
    unsigned short* T1s  = (unsigned short*)(p + 25165824);    //    131,072 B
    unsigned short* T1d  = (unsigned short*)(p + 25296896);
    unsigned short* T2s  = (unsigned short*)(p + 25427968);
    unsigned short* T2d  = (unsigned short*)(p + 25559040);
    unsigned short* Tfc  = (unsigned short*)(p + 25690112);    //     32,768 B
    int* counts  = (int*)(p + 25722880);
    int* row_ptr = counts + 512;
    int* fill    = row_ptr + 513;
    int* eidx    = fill + 512;
    const size_t base = 25755648;

    // per-seq-chunk bytes: 3*524288 + 65536 + 2*131072 + 262144 + 131072 = 2,293,760
    int SC = 1;
    const int cand[7] = {64, 32, 16, 8, 4, 2, 1};
    for (int i = 0; i < 7; ++i)
        if (base + (size_t)cand[i] * 2293760ull <= ws_size) { SC = cand[i]; break; }

    unsigned short* FSb  = (unsigned short*)(p + base);
    unsigned short* FDb  = FSb  + (size_t)SC * 262144;
    unsigned short* G1b  = FDb  + (size_t)SC * 262144;
    float*          LOG  = (float*)(G1b + (size_t)SC * 262144);
    unsigned short* FS2b = (unsigned short*)((char*)LOG + (size_t)SC * 65536);
    unsigned short* FD2b = FS2b + (size_t)SC * 65536;
    float*          G2   = (float*)(FD2b + (size_t)SC * 65536);
    unsigned short* Ybf  = (unsigned short*)((char*)G2 + (size_t)SC * 262144);

    preprocess_k<<<4096, 256, 0, stream>>>(x, H, Hbf);
    castw_k<<<1088, 256, 0, stream>>>(W1s, W1d, W2s, W2d, Wfc, T1s, T1d, T2s, T2d, Tfc);
    csr_init_k<<<1, 512, 0, stream>>>(counts, fill);
    csr_hist_k<<<NE / 256, 256, 0, stream>>>(dst, counts);
    csr_scan_k<<<1, 64, 0, stream>>>(counts, row_ptr);
    csr_scatter_k<<<NE / 256, 256, 0, stream>>>(dst, row_ptr, fill, eidx);

    for (int s0 = 0; s0 < SEQL; s0 += SC) {
        const unsigned short* Hc = Hbf + (size_t)s0 * NN * DIN;
        int M = SC * NN;
        gemm_k<0><<<dim3(4, SC * 4), 256, 0, stream>>>(Hc, T1s, b1s, FSb, M, 512, 128, 0);
        gemm_k<0><<<dim3(4, SC * 4), 256, 0, stream>>>(Hc, T1d, b1d, FDb, M, 512, 128, 0);
        edge_logits1_k<<<SC * 1024, 256, 0, stream>>>(FSb, FDb, src, dst, attn1, LOG, SC);
        node_agg1_k<<<SC * 512, 256, 0, stream>>>(FSb, LOG, src, row_ptr, eidx, G1b, SC);
        gemm_k<0><<<dim3(1, SC * 4), 256, 0, stream>>>(G1b, T2s, b2s, FS2b, M, 128, 512, 0);
        gemm_k<0><<<dim3(1, SC * 4), 256, 0, stream>>>(G1b, T2d, b2d, FD2b, M, 128, 512, 0);
        edge_logits2_k<<<SC * 1024, 256, 0, stream>>>(FS2b, FD2b, src, dst, attn2, LOG, SC);
        node_agg2_k<<<SC * 128, 256, 0, stream>>>(FS2b, LOG, src, row_ptr, eidx, G2, SC);
        ln_k<<<SC * 512, 128, 0, stream>>>(H, G2, gamma, beta, Ybf, s0);
        gemm_k<1><<<dim3(1, SC * 4), 256, 0, stream>>>(Ybf, Tfc, bfc, out, M, 128, 128, s0);
    }
}

// Round 6
// 337.275 us; speedup vs baseline: 2.2093x; 1.0939x over previous
//
#include <hip/hip_runtime.h>
#include <cmath>

#define NN    512
#define SEQL  64
#define DIN   128
#define NH    4
#define NE    4096
#define DOUTN 128

typedef __attribute__((ext_vector_type(4))) float f32x4;
typedef __attribute__((ext_vector_type(8))) short bf16x8;

__device__ __forceinline__ float lrelu(float v) { return v >= 0.f ? v : 0.2f * v; }

__device__ __forceinline__ unsigned short f2bf(float f) {
    union { float f; unsigned u; } x; x.f = f;
    unsigned r = (x.u + 0x7FFFu + ((x.u >> 16) & 1u)) >> 16;
    return (unsigned short)r;
}
__device__ __forceinline__ float bf2f(unsigned short h) {
    union { unsigned u; float f; } x; x.u = ((unsigned)h) << 16;
    return x.f;
}

// ---------------- preprocess: x[N][S][D] -> H f32 [S][N][D] + Hbf bf16 [S][N][D]
__global__ __launch_bounds__(256) void preprocess_k(const float* __restrict__ x,
                                                    float* __restrict__ H,
                                                    unsigned short* __restrict__ Hbf) {
    int tid = blockIdx.x * 256 + threadIdx.x;       // over 1,048,576 (4 elems each)
    int base = tid * 4;
    int d0 = base & 127;
    int s  = (base >> 7) & 63;
    int n  = base >> 13;
    float4 v = *(const float4*)(x + base);
    if (d0 == 0) {
        v.y = log10f(v.y + 1.f); v.z = log10f(v.z + 1.f); v.w = log10f(v.w + 1.f);
    } else {
        v.x = log10f(v.x + 1.f); v.y = log10f(v.y + 1.f);
        v.z = log10f(v.z + 1.f); v.w = log10f(v.w + 1.f);
    }
    if (v.x != v.x) v.x = 0.f;
    if (v.y != v.y) v.y = 0.f;
    if (v.z != v.z) v.z = 0.f;
    if (v.w != v.w) v.w = 0.f;
    size_t off = ((size_t)s * NN + n) * DIN + d0;
    *(float4*)(H + off) = v;
    ushort4 b; b.x = f2bf(v.x); b.y = f2bf(v.y); b.z = f2bf(v.z); b.w = f2bf(v.w);
    *(ushort4*)(Hbf + off) = b;
}

// ---------------- weight cast + transpose + concat: T1sd[1024][128], T2sd[256][512], Tfc[128][128]
__global__ __launch_bounds__(256) void castw_k(const float* __restrict__ W1s, const float* __restrict__ W1d,
                                               const float* __restrict__ W2s, const float* __restrict__ W2d,
                                               const float* __restrict__ Wfc,
                                               const float* __restrict__ b1s, const float* __restrict__ b1d,
                                               const float* __restrict__ b2s, const float* __restrict__ b2d,
                                               unsigned short* __restrict__ T1sd, unsigned short* __restrict__ T2sd,
                                               unsigned short* __restrict__ Tfc,
                                               float* __restrict__ bc1, float* __restrict__ bc2) {
    int i = blockIdx.x * 256 + threadIdx.x;          // 279,808 total
    if (i < 131072) {                                 // T1sd[1024][128]
        int n = i >> 7, k = i & 127;
        T1sd[i] = f2bf(n < 512 ? W1s[k * 512 + n] : W1d[k * 512 + (n - 512)]);
    } else if (i < 262144) {                          // T2sd[256][512]
        int j = i - 131072; int n = j >> 9, k = j & 511;
        T2sd[j] = f2bf(n < 128 ? W2s[k * 128 + n] : W2d[k * 128 + (n - 128)]);
    } else if (i < 278528) {                          // Tfc[128][128]
        int j = i - 262144; int n = j >> 7, k = j & 127;
        Tfc[j] = f2bf(Wfc[k * 128 + n]);
    } else if (i < 279552) {                          // bc1[1024]
        int j = i - 278528;
        bc1[j] = j < 512 ? b1s[j] : b1d[j - 512];
    } else if (i < 279808) {                          // bc2[256]
        int j = i - 279552;
        bc2[j] = j < 128 ? b2s[j] : b2d[j - 128];
    }
}

// ---------------- CSR build
__global__ void csr_init_k(int* counts, int* fill) {
    int t = threadIdx.x;
    counts[t] = 0; fill[t] = 0;
}
__global__ void csr_hist_k(const int* __restrict__ dst, int* counts) {
    int e = blockIdx.x * 256 + threadIdx.x;
    if (e < NE) atomicAdd(&counts[dst[e]], 1);
}
__global__ void csr_scan_k(const int* __restrict__ counts, int* __restrict__ row_ptr) {
    int l = threadIdx.x;                              // 64 lanes
    int c[8]; int lsum = 0;
#pragma unroll
    for (int j = 0; j < 8; ++j) { c[j] = counts[l * 8 + j]; lsum += c[j]; }
    int pre = lsum;
    for (int o = 1; o < 64; o <<= 1) {
        int v = __shfl_up(pre, o);
        if (l >= o) pre += v;
    }
    int acc = pre - lsum;                             // exclusive
#pragma unroll
    for (int j = 0; j < 8; ++j) { row_ptr[l * 8 + j] = acc; acc += c[j]; }
    if (l == 63) row_ptr[512] = acc;
}
__global__ void csr_scatter_k(const int* __restrict__ dst, const int* __restrict__ row_ptr,
                              int* fill, int* eidx) {
    int e = blockIdx.x * 256 + threadIdx.x;
    if (e < NE) {
        int dn = dst[e];
        int pos = atomicAdd(&fill[dn], 1);
        eidx[row_ptr[dn] + pos] = e;
    }
}

// ---------------- bf16 MFMA GEMM: C = A[M,K] @ BT[N,K]^T + bias
// MODE 0: single bf16 out (C1). MODE 1: f32 remap out (final FC). MODE 2: split bf16 (C1|C2 at half).
template<int MODE>
__global__ __launch_bounds__(256) void gemm_k(const unsigned short* __restrict__ A,
                                              const unsigned short* __restrict__ BT,
                                              const float* __restrict__ bias,
                                              void* __restrict__ C1v, void* __restrict__ C2v,
                                              int M, int N, int K, int s0, int half) {
    __shared__ unsigned short As[8192];   // 128 rows x 64 cols (phys-swizzled), 16 KB
    __shared__ unsigned short Bs[8192];
    int t = threadIdx.x;
    int w = t >> 6, l = t & 63;
    int wr = w >> 1, wc = w & 1;
    int m0 = blockIdx.y * 128, n0 = blockIdx.x * 128;

    f32x4 acc[4][4];
#pragma unroll
    for (int i = 0; i < 4; ++i)
#pragma unroll
        for (int j = 0; j < 4; ++j) acc[i][j] = (f32x4){0.f, 0.f, 0.f, 0.f};

    for (int k0 = 0; k0 < K; k0 += 64) {
        bf16x8 ra[4], rb[4];
#pragma unroll
        for (int r = 0; r < 4; ++r) {
            int q = t * 16 + r * 4096;                 // logical byte in 16 KB tile
            int row = q >> 7;                          // 0..127
            int cole = (q & 127) >> 1;                 // element col (8-aligned)
            ra[r] = *(const bf16x8*)(A  + (size_t)(m0 + row) * K + k0 + cole);
            rb[r] = *(const bf16x8*)(BT + (size_t)(n0 + row) * K + k0 + cole);
        }
        __syncthreads();                               // previous compute done
#pragma unroll
        for (int r = 0; r < 4; ++r) {
            int q = t * 16 + r * 4096;
            int row = q >> 7;
            int phys = (row << 7) | ((q & 127) ^ ((row & 7) << 4));
            *(bf16x8*)((char*)As + phys) = ra[r];
            *(bf16x8*)((char*)Bs + phys) = rb[r];
        }
        __syncthreads();
#pragma unroll
        for (int ks = 0; ks < 2; ++ks) {
            bf16x8 af[4], bfr[4];
#pragma unroll
            for (int i = 0; i < 4; ++i) {
                int row = wr * 64 + i * 16 + (l & 15);
                int colb = (ks * 64 + ((l >> 4) * 16)) ^ ((row & 7) << 4);
                af[i] = *(const bf16x8*)((const char*)As + (row << 7) + colb);
            }
#pragma unroll
            for (int j = 0; j < 4; ++j) {
                int row = wc * 64 + j * 16 + (l & 15);
                int colb = (ks * 64 + ((l >> 4) * 16)) ^ ((row & 7) << 4);
                bfr[j] = *(const bf16x8*)((const char*)Bs + (row << 7) + colb);
            }
#pragma unroll
            for (int i = 0; i < 4; ++i)
#pragma unroll
                for (int j = 0; j < 4; ++j)
                    acc[i][j] = __builtin_amdgcn_mfma_f32_16x16x32_bf16(af[i], bfr[j], acc[i][j], 0, 0, 0);
        }
    }

    float bl[4];
#pragma unroll
    for (int j = 0; j < 4; ++j) bl[j] = bias[n0 + wc * 64 + j * 16 + (l & 15)];
#pragma unroll
    for (int i = 0; i < 4; ++i) {
#pragma unroll
        for (int j = 0; j < 4; ++j) {
            int n = n0 + wc * 64 + j * 16 + (l & 15);
#pragma unroll
            for (int jj = 0; jj < 4; ++jj) {
                int m = m0 + wr * 64 + i * 16 + (l >> 4) * 4 + jj;
                float v = acc[i][j][jj] + bl[j];
                if (MODE == 1) {
                    int sl = m >> 9, node = m & 511;
                    ((float*)C1v)[((size_t)node * SEQL + (s0 + sl)) * DOUTN + n] = v;
                } else if (MODE == 2) {
                    unsigned short* dp = (unsigned short*)(n < half ? C1v : C2v);
                    int nn = n < half ? n : n - half;
                    dp[(size_t)m * half + nn] = f2bf(v);
                } else {
                    ((unsigned short*)C1v)[(size_t)m * N + n] = f2bf(v);
                }
            }
        }
    }
}

// ---------------- XCD-affine (s, idx) decode: B blocks per s, s%8 pinned to one XCD
__device__ __forceinline__ void s_swizzle(int bid, int sc, int B, int logB, int& s, int& idx) {
    if ((sc & 7) == 0) {
        int xcd = bid & 7;
        int j = bid >> 3;
        int grp = j >> logB;
        idx = j & (B - 1);
        s = grp * 8 + xcd;
    } else {
        s = bid >> logB;
        idx = bid & (B - 1);
    }
}

// ---------------- layer-1 edge logits: wave per (s,e); 4 heads x 128, bf16 in
__global__ __launch_bounds__(256) void edge_logits1_k(const unsigned short* __restrict__ FS,
                                                      const unsigned short* __restrict__ FD,
                                                      const int* __restrict__ src, const int* __restrict__ dst,
                                                      const float* __restrict__ attn, float* __restrict__ LOG,
                                                      int sc) {
    int w = threadIdx.x >> 6, l = threadIdx.x & 63;
    int s, eb;
    s_swizzle(blockIdx.x, sc, 1024, 10, s, eb);
    int e = eb * 4 + w;
    int sn = src[e], dn = dst[e];
    bf16x8 a = *(const bf16x8*)(FS + ((size_t)s * NN + sn) * 512 + l * 8);
    bf16x8 b = *(const bf16x8*)(FD + ((size_t)s * NN + dn) * 512 + l * 8);
    const float* at = attn + l * 8;
    float acc = 0.f;
#pragma unroll
    for (int j = 0; j < 8; ++j) {
        float v = bf2f((unsigned short)a[j]) + bf2f((unsigned short)b[j]);
        acc += at[j] * lrelu(v);
    }
#pragma unroll
    for (int o = 1; o < 16; o <<= 1) acc += __shfl_xor(acc, o);
    if ((l & 15) == 0) LOG[((size_t)s * NE + e) * 4 + (l >> 4)] = acc;
}

// ---------------- layer-1 softmax + agg: block per (s,n), wave = head; 16 f-lanes x 4 edge-groups
__global__ __launch_bounds__(256) void node_agg1_k(const unsigned short* __restrict__ FS,
                                                   const float* __restrict__ LOG,
                                                   const int* __restrict__ src, const int* __restrict__ row_ptr,
                                                   const int* __restrict__ eidx, unsigned short* __restrict__ G1,
                                                   int sc) {
    int s, n;
    s_swizzle(blockIdx.x, sc, 512, 9, s, n);
    int h = threadIdx.x >> 6, l = threadIdx.x & 63;
    int e0 = row_ptr[n], e1 = row_ptr[n + 1];
    const float* logs = LOG + (size_t)s * NE * 4;
    float m = -INFINITY;
    for (int j = e0 + l; j < e1; j += 64) m = fmaxf(m, logs[eidx[j] * 4 + h]);
    for (int o = 32; o > 0; o >>= 1) m = fmaxf(m, __shfl_xor(m, o));
    float den = 0.f;
    for (int j = e0 + l; j < e1; j += 64) den += expf(logs[eidx[j] * 4 + h] - m);
    for (int o = 32; o > 0; o >>= 1) den += __shfl_xor(den, o);
    float inv = 1.f / den;
    int eg = l >> 4, fl = l & 15;
    float acc[8] = {};
    for (int j = e0 + eg; j < e1; j += 4) {
        int e = eidx[j];
        float wgt = expf(logs[e * 4 + h] - m) * inv;
        bf16x8 row = *(const bf16x8*)(FS + ((size_t)s * NN + src[e]) * 512 + h * 128 + fl * 8);
#pragma unroll
        for (int k = 0; k < 8; ++k) acc[k] += wgt * bf2f((unsigned short)row[k]);
    }
#pragma unroll
    for (int k = 0; k < 8; ++k) {
        acc[k] += __shfl_xor(acc[k], 16);
        acc[k] += __shfl_xor(acc[k], 32);
    }
    if (l < 16) {
        bf16x8 o8;
#pragma unroll
        for (int k = 0; k < 8; ++k) o8[k] = (short)f2bf(acc[k]);
        *(bf16x8*)(G1 + ((size_t)s * NN + n) * 512 + h * 128 + fl * 8) = o8;
    }
}

// ---------------- layer-2 edge logits (1 head, 128), wave per (s,e)
__global__ __launch_bounds__(256) void edge_logits2_k(const unsigned short* __restrict__ FS,
                                                      const unsigned short* __restrict__ FD,
                                                      const int* __restrict__ src, const int* __restrict__ dst,
                                                      const float* __restrict__ attn, float* __restrict__ LOG,
                                                      int sc) {
    int w = threadIdx.x >> 6, l = threadIdx.x & 63;
    int s, eb;
    s_swizzle(blockIdx.x, sc, 1024, 10, s, eb);
    int e = eb * 4 + w;
    ushort2 ua = *(const ushort2*)(FS + ((size_t)s * NN + src[e]) * 128 + l * 2);
    ushort2 ub = *(const ushort2*)(FD + ((size_t)s * NN + dst[e]) * 128 + l * 2);
    float acc = attn[l * 2] * lrelu(bf2f(ua.x) + bf2f(ub.x))
              + attn[l * 2 + 1] * lrelu(bf2f(ua.y) + bf2f(ub.y));
    for (int o = 32; o > 0; o >>= 1) acc += __shfl_xor(acc, o);
    if (l == 0) LOG[(size_t)s * NE + e] = acc;
}

// ---------------- layer-2 softmax + agg: wave per (s,n); 16 f-lanes x 4 edge-groups
__global__ __launch_bounds__(256) void node_agg2_k(const unsigned short* __restrict__ FS,
                                                   const float* __restrict__ LOG,
                                                   const int* __restrict__ src, const int* __restrict__ row_ptr,
                                                   const int* __restrict__ eidx, float* __restrict__ G2,
                                                   int sc) {
    int w = threadIdx.x >> 6, l = threadIdx.x & 63;
    int s, nb;
    s_swizzle(blockIdx.x, sc, 128, 7, s, nb);
    int n = nb * 4 + w;
    int e0 = row_ptr[n], e1 = row_ptr[n + 1];
    const float* logs = LOG + (size_t)s * NE;
    float m = -INFINITY;
    for (int j = e0 + l; j < e1; j += 64) m = fmaxf(m, logs[eidx[j]]);
    for (int o = 32; o > 0; o >>= 1) m = fmaxf(m, __shfl_xor(m, o));
    float den = 0.f;
    for (int j = e0 + l; j < e1; j += 64) den += expf(logs[eidx[j]] - m);
    for (int o = 32; o > 0; o >>= 1) den += __shfl_xor(den, o);
    float inv = 1.f / den;
    int eg = l >> 4, fl = l & 15;
    float acc[8] = {};
    for (int j = e0 + eg; j < e1; j += 4) {
        int e = eidx[j];
        float wgt = expf(logs[e] - m) * inv;
        bf16x8 row = *(const bf16x8*)(FS + ((size_t)s * NN + src[e]) * 128 + fl * 8);
#pragma unroll
        for (int k = 0; k < 8; ++k) acc[k] += wgt * bf2f((unsigned short)row[k]);
    }
#pragma unroll
    for (int k = 0; k < 8; ++k) {
        acc[k] += __shfl_xor(acc[k], 16);
        acc[k] += __shfl_xor(acc[k], 32);
    }
    if (l < 16) {
        float* outr = G2 + ((size_t)s * NN + n) * 128 + fl * 8;
        *(f32x4*)outr       = (f32x4){acc[0], acc[1], acc[2], acc[3]};
        *(f32x4*)(outr + 4) = (f32x4){acc[4], acc[5], acc[6], acc[7]};
    }
}

// ---------------- residual + NaN-guard + LayerNorm -> bf16 Y
__global__ __launch_bounds__(128) void ln_k(const float* __restrict__ H, const float* __restrict__ G2,
                                            const float* __restrict__ gamma, const float* __restrict__ beta,
                                            unsigned short* __restrict__ Y, int s0) {
    int b = blockIdx.x;                 // sc*512
    int sl = b >> 9, n = b & 511;
    int t = threadIdx.x;                // 128
    __shared__ float red[4];
    float xp = H[((size_t)(s0 + sl) * NN + n) * DIN + t];
    float g  = G2[((size_t)sl * NN + n) * DIN + t];
    if (g != g) g = xp;
    float o = xp + g;
    float ssum = o, ssq = o * o;
    for (int off = 32; off > 0; off >>= 1) { ssum += __shfl_xor(ssum, off); ssq += __shfl_xor(ssq, off); }
    if ((t & 63) == 0) { red[(t >> 6) * 2] = ssum; red[(t >> 6) * 2 + 1] = ssq; }
    __syncthreads();
    float S = red[0] + red[2], Q = red[1] + red[3];
    float mu = S * (1.f / 128.f);
    float var = Q * (1.f / 128.f) - mu * mu;
    float y = (o - mu) * rsqrtf(var + 1e-5f) * gamma[t] + beta[t];
    Y[((size_t)sl * NN + n) * DIN + t] = f2bf(y);
}

extern "C" void kernel_launch(void* const* d_in, const int* in_sizes, int n_in,
                              void* d_out, int out_size, void* d_ws, size_t ws_size,
                              hipStream_t stream) {
    const float* x     = (const float*)d_in[0];
    const int*   src   = (const int*)d_in[1];
    const int*   dst   = (const int*)d_in[2];
    const float* W1s   = (const float*)d_in[3];
    const float* b1s   = (const float*)d_in[4];
    const float* W1d   = (const float*)d_in[5];
    const float* b1d   = (const float*)d_in[6];
    const float* attn1 = (const float*)d_in[7];
    const float* W2s   = (const float*)d_in[8];
    const float* b2s   = (const float*)d_in[9];
    const float* W2d   = (const float*)d_in[10];
    const float* b2d   = (const float*)d_in[11];
    const float* attn2 = (const float*)d_in[12];
    const float* gamma = (const float*)d_in[13];
    const float* beta  = (const float*)d_in[14];
    const float* Wfc   = (const float*)d_in[15];
    const float* bfc   = (const float*)d_in[16];
    float* out = (float*)d_out;

    char* p = (char*)d_ws;
    float*          H    = (float*)p;                          // 16,777,216 B
    unsigned short* Hbf  = (unsigned short*)(p + 16777216);    //  8,388,608 B
    unsigned short* T1sd = (unsigned short*)(p + 25165824);    //    262,144 B
    unsigned short* T2sd = (unsigned short*)(p + 25427968);    //    262,144 B
    unsigned short* Tfc  = (unsigned short*)(p + 25690112);    //     32,768 B
    float*          bc1  = (float*)(p + 25722880);             //      4,096 B
    float*          bc2  = (float*)(p + 25726976);             //      1,024 B
    int* counts  = (int*)(p + 25728000);
    int* row_ptr = counts + 512;
    int* fill    = row_ptr + 513;
    int* eidx    = fill + 512;                                 // ends 25,750,532
    const size_t base = 25755648;

    // per-seq-chunk bytes: 3*524288 + 65536 + 2*131072 + 262144 + 131072 = 2,293,760
    int SC = 1;
    const int cand[7] = {64, 32, 16, 8, 4, 2, 1};
    for (int i = 0; i < 7; ++i)
        if (base + (size_t)cand[i] * 2293760ull <= ws_size) { SC = cand[i]; break; }

    unsigned short* FSb  = (unsigned short*)(p + base);
    unsigned short* FDb  = FSb  + (size_t)SC * 262144;
    unsigned short* G1b  = FDb  + (size_t)SC * 262144;
    float*          LOG  = (float*)(G1b + (size_t)SC * 262144);
    unsigned short* FS2b = (unsigned short*)((char*)LOG + (size_t)SC * 65536);
    unsigned short* FD2b = FS2b + (size_t)SC * 65536;
    float*          G2   = (float*)(FD2b + (size_t)SC * 65536);
    unsigned short* Ybf  = (unsigned short*)((char*)G2 + (size_t)SC * 262144);

    preprocess_k<<<4096, 256, 0, stream>>>(x, H, Hbf);
    castw_k<<<1094, 256, 0, stream>>>(W1s, W1d, W2s, W2d, Wfc, b1s, b1d, b2s, b2d,
                                      T1sd, T2sd, Tfc, bc1, bc2);
    csr_init_k<<<1, 512, 0, stream>>>(counts, fill);
    csr_hist_k<<<NE / 256, 256, 0, stream>>>(dst, counts);
    csr_scan_k<<<1, 64, 0, stream>>>(counts, row_ptr);
    csr_scatter_k<<<NE / 256, 256, 0, stream>>>(dst, row_ptr, fill, eidx);

    for (int s0 = 0; s0 < SEQL; s0 += SC) {
        const unsigned short* Hc = Hbf + (size_t)s0 * NN * DIN;
        int M = SC * NN;
        gemm_k<2><<<dim3(8, SC * 4), 256, 0, stream>>>(Hc, T1sd, bc1, FSb, FDb, M, 1024, 128, 0, 512);
        edge_logits1_k<<<SC * 1024, 256, 0, stream>>>(FSb, FDb, src, dst, attn1, LOG, SC);
        node_agg1_k<<<SC * 512, 256, 0, stream>>>(FSb, LOG, src, row_ptr, eidx, G1b, SC);
        gemm_k<2><<<dim3(2, SC * 4), 256, 0, stream>>>(G1b, T2sd, bc2, FS2b, FD2b, M, 256, 512, 0, 128);
        edge_logits2_k<<<SC * 1024, 256, 0, stream>>>(FS2b, FD2b, src, dst, attn2, LOG, SC);
        node_agg2_k<<<SC * 128, 256, 0, stream>>>(FS2b, LOG, src, row_ptr, eidx, G2, SC);
        ln_k<<<SC * 512, 128, 0, stream>>>(H, G2, gamma, beta, Ybf, s0);
        gemm_k<1><<<dim3(1, SC * 4), 256, 0, stream>>>(Ybf, Tfc, bfc, out, nullptr, M, 128, 128, s0, 0);
    }
}

// Round 7
// 331.915 us; speedup vs baseline: 2.2450x; 1.0161x over previous
//
#include <hip/hip_runtime.h>
#include <cmath>

#define NN    512
#define SEQL  64
#define DIN   128
#define NH    4
#define NE    4096
#define DOUTN 128

typedef __attribute__((ext_vector_type(4))) float f32x4;
typedef __attribute__((ext_vector_type(8))) short bf16x8;

__device__ __forceinline__ float lrelu(float v) { return v >= 0.f ? v : 0.2f * v; }

__device__ __forceinline__ unsigned short f2bf(float f) {
    union { float f; unsigned u; } x; x.f = f;
    unsigned r = (x.u + 0x7FFFu + ((x.u >> 16) & 1u)) >> 16;
    return (unsigned short)r;
}
__device__ __forceinline__ float bf2f(unsigned short h) {
    union { unsigned u; float f; } x; x.u = ((unsigned)h) << 16;
    return x.f;
}

// ---------------- preprocess: x[N][S][D] -> H f32 [S][N][D] + Hbf bf16 [S][N][D]
__global__ __launch_bounds__(256) void preprocess_k(const float* __restrict__ x,
                                                    float* __restrict__ H,
                                                    unsigned short* __restrict__ Hbf) {
    int tid = blockIdx.x * 256 + threadIdx.x;       // over 1,048,576 (4 elems each)
    int base = tid * 4;
    int d0 = base & 127;
    int s  = (base >> 7) & 63;
    int n  = base >> 13;
    float4 v = *(const float4*)(x + base);
    if (d0 == 0) {
        v.y = log10f(v.y + 1.f); v.z = log10f(v.z + 1.f); v.w = log10f(v.w + 1.f);
    } else {
        v.x = log10f(v.x + 1.f); v.y = log10f(v.y + 1.f);
        v.z = log10f(v.z + 1.f); v.w = log10f(v.w + 1.f);
    }
    if (v.x != v.x) v.x = 0.f;
    if (v.y != v.y) v.y = 0.f;
    if (v.z != v.z) v.z = 0.f;
    if (v.w != v.w) v.w = 0.f;
    size_t off = ((size_t)s * NN + n) * DIN + d0;
    *(float4*)(H + off) = v;
    ushort4 b; b.x = f2bf(v.x); b.y = f2bf(v.y); b.z = f2bf(v.z); b.w = f2bf(v.w);
    *(ushort4*)(Hbf + off) = b;
}

// ---------------- weight cast + transpose + concat: T1sd[1024][128], T2sd[256][512], Tfc[128][128]
__global__ __launch_bounds__(256) void castw_k(const float* __restrict__ W1s, const float* __restrict__ W1d,
                                               const float* __restrict__ W2s, const float* __restrict__ W2d,
                                               const float* __restrict__ Wfc,
                                               const float* __restrict__ b1s, const float* __restrict__ b1d,
                                               const float* __restrict__ b2s, const float* __restrict__ b2d,
                                               unsigned short* __restrict__ T1sd, unsigned short* __restrict__ T2sd,
                                               unsigned short* __restrict__ Tfc,
                                               float* __restrict__ bc1, float* __restrict__ bc2) {
    int i = blockIdx.x * 256 + threadIdx.x;          // 279,808 total
    if (i < 131072) {                                 // T1sd[1024][128]
        int n = i >> 7, k = i & 127;
        T1sd[i] = f2bf(n < 512 ? W1s[k * 512 + n] : W1d[k * 512 + (n - 512)]);
    } else if (i < 262144) {                          // T2sd[256][512]
        int j = i - 131072; int n = j >> 9, k = j & 511;
        T2sd[j] = f2bf(n < 128 ? W2s[k * 128 + n] : W2d[k * 128 + (n - 128)]);
    } else if (i < 278528) {                          // Tfc[128][128]
        int j = i - 262144; int n = j >> 7, k = j & 127;
        Tfc[j] = f2bf(Wfc[k * 128 + n]);
    } else if (i < 279552) {                          // bc1[1024]
        int j = i - 278528;
        bc1[j] = j < 512 ? b1s[j] : b1d[j - 512];
    } else if (i < 279808) {                          // bc2[256]
        int j = i - 279552;
        bc2[j] = j < 128 ? b2s[j] : b2d[j - 128];
    }
}

// ---------------- CSR build
__global__ void csr_init_k(int* counts, int* fill) {
    int t = threadIdx.x;
    counts[t] = 0; fill[t] = 0;
}
__global__ void csr_hist_k(const int* __restrict__ dst, int* counts) {
    int e = blockIdx.x * 256 + threadIdx.x;
    if (e < NE) atomicAdd(&counts[dst[e]], 1);
}
__global__ void csr_scan_k(const int* __restrict__ counts, int* __restrict__ row_ptr) {
    int l = threadIdx.x;                              // 64 lanes
    int c[8]; int lsum = 0;
#pragma unroll
    for (int j = 0; j < 8; ++j) { c[j] = counts[l * 8 + j]; lsum += c[j]; }
    int pre = lsum;
    for (int o = 1; o < 64; o <<= 1) {
        int v = __shfl_up(pre, o);
        if (l >= o) pre += v;
    }
    int acc = pre - lsum;                             // exclusive
#pragma unroll
    for (int j = 0; j < 8; ++j) { row_ptr[l * 8 + j] = acc; acc += c[j]; }
    if (l == 63) row_ptr[512] = acc;
}
__global__ void csr_scatter_k(const int* __restrict__ dst, const int* __restrict__ row_ptr,
                              int* fill, int* eidx) {
    int e = blockIdx.x * 256 + threadIdx.x;
    if (e < NE) {
        int dn = dst[e];
        int pos = atomicAdd(&fill[dn], 1);
        eidx[row_ptr[dn] + pos] = e;
    }
}

// ---------------- bf16 MFMA GEMM: C = A[M,K] @ BT[N,K]^T + bias
// MODE 0: single bf16 out (C1). MODE 1: f32 remap out (final FC). MODE 2: split bf16 (C1|C2 at half).
template<int MODE>
__global__ __launch_bounds__(256) void gemm_k(const unsigned short* __restrict__ A,
                                              const unsigned short* __restrict__ BT,
                                              const float* __restrict__ bias,
                                              void* __restrict__ C1v, void* __restrict__ C2v,
                                              int M, int N, int K, int s0, int half) {
    __shared__ unsigned short As[8192];   // 128 rows x 64 cols (phys-swizzled), 16 KB
    __shared__ unsigned short Bs[8192];
    int t = threadIdx.x;
    int w = t >> 6, l = t & 63;
    int wr = w >> 1, wc = w & 1;
    int m0 = blockIdx.y * 128, n0 = blockIdx.x * 128;

    f32x4 acc[4][4];
#pragma unroll
    for (int i = 0; i < 4; ++i)
#pragma unroll
        for (int j = 0; j < 4; ++j) acc[i][j] = (f32x4){0.f, 0.f, 0.f, 0.f};

    for (int k0 = 0; k0 < K; k0 += 64) {
        bf16x8 ra[4], rb[4];
#pragma unroll
        for (int r = 0; r < 4; ++r) {
            int q = t * 16 + r * 4096;                 // logical byte in 16 KB tile
            int row = q >> 7;                          // 0..127
            int cole = (q & 127) >> 1;                 // element col (8-aligned)
            ra[r] = *(const bf16x8*)(A  + (size_t)(m0 + row) * K + k0 + cole);
            rb[r] = *(const bf16x8*)(BT + (size_t)(n0 + row) * K + k0 + cole);
        }
        __syncthreads();                               // previous compute done
#pragma unroll
        for (int r = 0; r < 4; ++r) {
            int q = t * 16 + r * 4096;
            int row = q >> 7;
            int phys = (row << 7) | ((q & 127) ^ ((row & 7) << 4));
            *(bf16x8*)((char*)As + phys) = ra[r];
            *(bf16x8*)((char*)Bs + phys) = rb[r];
        }
        __syncthreads();
#pragma unroll
        for (int ks = 0; ks < 2; ++ks) {
            bf16x8 af[4], bfr[4];
#pragma unroll
            for (int i = 0; i < 4; ++i) {
                int row = wr * 64 + i * 16 + (l & 15);
                int colb = (ks * 64 + ((l >> 4) * 16)) ^ ((row & 7) << 4);
                af[i] = *(const bf16x8*)((const char*)As + (row << 7) + colb);
            }
#pragma unroll
            for (int j = 0; j < 4; ++j) {
                int row = wc * 64 + j * 16 + (l & 15);
                int colb = (ks * 64 + ((l >> 4) * 16)) ^ ((row & 7) << 4);
                bfr[j] = *(const bf16x8*)((const char*)Bs + (row << 7) + colb);
            }
#pragma unroll
            for (int i = 0; i < 4; ++i)
#pragma unroll
                for (int j = 0; j < 4; ++j)
                    acc[i][j] = __builtin_amdgcn_mfma_f32_16x16x32_bf16(af[i], bfr[j], acc[i][j], 0, 0, 0);
        }
    }

    float bl[4];
#pragma unroll
    for (int j = 0; j < 4; ++j) bl[j] = bias[n0 + wc * 64 + j * 16 + (l & 15)];
#pragma unroll
    for (int i = 0; i < 4; ++i) {
#pragma unroll
        for (int j = 0; j < 4; ++j) {
            int n = n0 + wc * 64 + j * 16 + (l & 15);
#pragma unroll
            for (int jj = 0; jj < 4; ++jj) {
                int m = m0 + wr * 64 + i * 16 + (l >> 4) * 4 + jj;
                float v = acc[i][j][jj] + bl[j];
                if (MODE == 1) {
                    int sl = m >> 9, node = m & 511;
                    ((float*)C1v)[((size_t)node * SEQL + (s0 + sl)) * DOUTN + n] = v;
                } else if (MODE == 2) {
                    unsigned short* dp = (unsigned short*)(n < half ? C1v : C2v);
                    int nn = n < half ? n : n - half;
                    dp[(size_t)m * half + nn] = f2bf(v);
                } else {
                    ((unsigned short*)C1v)[(size_t)m * N + n] = f2bf(v);
                }
            }
        }
    }
}

// ---------------- XCD-affine (s, idx) decode: B blocks per s, s%8 pinned to one XCD
__device__ __forceinline__ void s_swizzle(int bid, int sc, int B, int logB, int& s, int& idx) {
    if ((sc & 7) == 0) {
        int xcd = bid & 7;
        int j = bid >> 3;
        int grp = j >> logB;
        idx = j & (B - 1);
        s = grp * 8 + xcd;
    } else {
        s = bid >> logB;
        idx = bid & (B - 1);
    }
}

// ---------------- layer-1 edge logits: wave per (s,e); 4 heads x 128, bf16 in
__global__ __launch_bounds__(256) void edge_logits1_k(const unsigned short* __restrict__ FS,
                                                      const unsigned short* __restrict__ FD,
                                                      const int* __restrict__ src, const int* __restrict__ dst,
                                                      const float* __restrict__ attn, float* __restrict__ LOG,
                                                      int sc) {
    int w = threadIdx.x >> 6, l = threadIdx.x & 63;
    int s, eb;
    s_swizzle(blockIdx.x, sc, 1024, 10, s, eb);
    int e = eb * 4 + w;
    int sn = src[e], dn = dst[e];
    bf16x8 a = *(const bf16x8*)(FS + ((size_t)s * NN + sn) * 512 + l * 8);
    bf16x8 b = *(const bf16x8*)(FD + ((size_t)s * NN + dn) * 512 + l * 8);
    const float* at = attn + l * 8;
    float acc = 0.f;
#pragma unroll
    for (int j = 0; j < 8; ++j) {
        float v = bf2f((unsigned short)a[j]) + bf2f((unsigned short)b[j]);
        acc += at[j] * lrelu(v);
    }
#pragma unroll
    for (int o = 1; o < 16; o <<= 1) acc += __shfl_xor(acc, o);
    if ((l & 15) == 0) LOG[((size_t)s * NE + e) * 4 + (l >> 4)] = acc;
}

// ---------------- layer-1 softmax+agg v3: ONE WAVE per (s,n), all 4 heads in-lane,
// single-pass online softmax (no shuffles, one expf/edge, one coalesced 1KB gather/edge)
__global__ __launch_bounds__(256) void node_agg1_k(const unsigned short* __restrict__ FS,
                                                   const float* __restrict__ LOG,
                                                   const int* __restrict__ src, const int* __restrict__ row_ptr,
                                                   const int* __restrict__ eidx, unsigned short* __restrict__ G1,
                                                   int sc) {
    int wv = threadIdx.x >> 6, l = threadIdx.x & 63;
    int s, nb;
    s_swizzle(blockIdx.x, sc, 128, 7, s, nb);
    int n = nb * 4 + wv;
    int h = l >> 4, fl = l & 15;
    int e0 = row_ptr[n], e1 = row_ptr[n + 1];
    const float* logs = LOG + (size_t)s * NE * 4;
    const unsigned short* fsbase = FS + (size_t)s * NN * 512 + h * 128 + fl * 8;
    float m_run = -INFINITY, den = 0.f;
    float acc[8] = {};
    for (int j = e0; j < e1; ++j) {
        int e = eidx[j];
        float lg = logs[e * 4 + h];
        float wgt;
        if (lg > m_run) {                      // rescale (uniform within 16-lane head group)
            float sc_ = expf(m_run - lg);      // first edge: exp(-inf)=0
            den *= sc_;
#pragma unroll
            for (int k = 0; k < 8; ++k) acc[k] *= sc_;
            m_run = lg;
            wgt = 1.f;
        } else {
            wgt = expf(lg - m_run);
        }
        den += wgt;
        bf16x8 row = *(const bf16x8*)(fsbase + (size_t)src[e] * 512);
#pragma unroll
        for (int k = 0; k < 8; ++k) acc[k] += wgt * bf2f((unsigned short)row[k]);
    }
    float inv = 1.f / den;
    bf16x8 o8;
#pragma unroll
    for (int k = 0; k < 8; ++k) o8[k] = (short)f2bf(acc[k] * inv);
    *(bf16x8*)(G1 + ((size_t)s * NN + n) * 512 + h * 128 + fl * 8) = o8;
}

// ---------------- layer-2 edge logits (1 head, 128), wave per (s,e)
__global__ __launch_bounds__(256) void edge_logits2_k(const unsigned short* __restrict__ FS,
                                                      const unsigned short* __restrict__ FD,
                                                      const int* __restrict__ src, const int* __restrict__ dst,
                                                      const float* __restrict__ attn, float* __restrict__ LOG,
                                                      int sc) {
    int w = threadIdx.x >> 6, l = threadIdx.x & 63;
    int s, eb;
    s_swizzle(blockIdx.x, sc, 1024, 10, s, eb);
    int e = eb * 4 + w;
    ushort2 ua = *(const ushort2*)(FS + ((size_t)s * NN + src[e]) * 128 + l * 2);
    ushort2 ub = *(const ushort2*)(FD + ((size_t)s * NN + dst[e]) * 128 + l * 2);
    float acc = attn[l * 2] * lrelu(bf2f(ua.x) + bf2f(ub.x))
              + attn[l * 2 + 1] * lrelu(bf2f(ua.y) + bf2f(ub.y));
    for (int o = 32; o > 0; o >>= 1) acc += __shfl_xor(acc, o);
    if (l == 0) LOG[(size_t)s * NE + e] = acc;
}

// ---------------- layer-2 softmax+agg v3: ONE WAVE per (s,n), single-pass online softmax
__global__ __launch_bounds__(256) void node_agg2_k(const unsigned short* __restrict__ FS,
                                                   const float* __restrict__ LOG,
                                                   const int* __restrict__ src, const int* __restrict__ row_ptr,
                                                   const int* __restrict__ eidx, float* __restrict__ G2,
                                                   int sc) {
    int wv = threadIdx.x >> 6, l = threadIdx.x & 63;
    int s, nb;
    s_swizzle(blockIdx.x, sc, 128, 7, s, nb);
    int n = nb * 4 + wv;
    int e0 = row_ptr[n], e1 = row_ptr[n + 1];
    const float* logs = LOG + (size_t)s * NE;
    const unsigned short* fb = FS + (size_t)s * NN * 128 + l * 2;
    float m_run = -INFINITY, den = 0.f, a0 = 0.f, a1 = 0.f;
    for (int j = e0; j < e1; ++j) {
        int e = eidx[j];
        float lg = logs[e];                    // uniform across wave
        float wgt;
        if (lg > m_run) {
            float sc_ = expf(m_run - lg);
            den *= sc_; a0 *= sc_; a1 *= sc_;
            m_run = lg;
            wgt = 1.f;
        } else {
            wgt = expf(lg - m_run);
        }
        den += wgt;
        ushort2 uv = *(const ushort2*)(fb + (size_t)src[e] * 128);
        a0 += wgt * bf2f(uv.x);
        a1 += wgt * bf2f(uv.y);
    }
    float inv = 1.f / den;
    float2 o2; o2.x = a0 * inv; o2.y = a1 * inv;
    *(float2*)(G2 + ((size_t)s * NN + n) * 128 + l * 2) = o2;
}

// ---------------- residual + NaN-guard + LayerNorm -> bf16 Y
__global__ __launch_bounds__(128) void ln_k(const float* __restrict__ H, const float* __restrict__ G2,
                                            const float* __restrict__ gamma, const float* __restrict__ beta,
                                            unsigned short* __restrict__ Y, int s0) {
    int b = blockIdx.x;                 // sc*512
    int sl = b >> 9, n = b & 511;
    int t = threadIdx.x;                // 128
    __shared__ float red[4];
    float xp = H[((size_t)(s0 + sl) * NN + n) * DIN + t];
    float g  = G2[((size_t)sl * NN + n) * DIN + t];
    if (g != g) g = xp;
    float o = xp + g;
    float ssum = o, ssq = o * o;
    for (int off = 32; off > 0; off >>= 1) { ssum += __shfl_xor(ssum, off); ssq += __shfl_xor(ssq, off); }
    if ((t & 63) == 0) { red[(t >> 6) * 2] = ssum; red[(t >> 6) * 2 + 1] = ssq; }
    __syncthreads();
    float S = red[0] + red[2], Q = red[1] + red[3];
    float mu = S * (1.f / 128.f);
    float var = Q * (1.f / 128.f) - mu * mu;
    float y = (o - mu) * rsqrtf(var + 1e-5f) * gamma[t] + beta[t];
    Y[((size_t)sl * NN + n) * DIN + t] = f2bf(y);
}

extern "C" void kernel_launch(void* const* d_in, const int* in_sizes, int n_in,
                              void* d_out, int out_size, void* d_ws, size_t ws_size,
                              hipStream_t stream) {
    const float* x     = (const float*)d_in[0];
    const int*   src   = (const int*)d_in[1];
    const int*   dst   = (const int*)d_in[2];
    const float* W1s   = (const float*)d_in[3];
    const float* b1s   = (const float*)d_in[4];
    const float* W1d   = (const float*)d_in[5];
    const float* b1d   = (const float*)d_in[6];
    const float* attn1 = (const float*)d_in[7];
    const float* W2s   = (const float*)d_in[8];
    const float* b2s   = (const float*)d_in[9];
    const float* W2d   = (const float*)d_in[10];
    const float* b2d   = (const float*)d_in[11];
    const float* attn2 = (const float*)d_in[12];
    const float* gamma = (const float*)d_in[13];
    const float* beta  = (const float*)d_in[14];
    const float* Wfc   = (const float*)d_in[15];
    const float* bfc   = (const float*)d_in[16];
    float* out = (float*)d_out;

    char* p = (char*)d_ws;
    float*          H    = (float*)p;                          // 16,777,216 B
    unsigned short* Hbf  = (unsigned short*)(p + 16777216);    //  8,388,608 B
    unsigned short* T1sd = (unsigned short*)(p + 25165824);    //    262,144 B
    unsigned short* T2sd = (unsigned short*)(p + 25427968);    //    262,144 B
    unsigned short* Tfc  = (unsigned short*)(p + 25690112);    //     32,768 B
    float*          bc1  = (float*)(p + 25722880);             //      4,096 B
    float*          bc2  = (float*)(p + 25726976);             //      1,024 B
    int* counts  = (int*)(p + 25728000);
    int* row_ptr = counts + 512;
    int* fill    = row_ptr + 513;
    int* eidx    = fill + 512;                                 // ends 25,750,532
    const size_t base = 25755648;

    // per-seq-chunk bytes: 3*524288 + 65536 + 2*131072 + 262144 + 131072 = 2,293,760
    int SC = 1;
    const int cand[7] = {64, 32, 16, 8, 4, 2, 1};
    for (int i = 0; i < 7; ++i)
        if (base + (size_t)cand[i] * 2293760ull <= ws_size) { SC = cand[i]; break; }

    unsigned short* FSb  = (unsigned short*)(p + base);
    unsigned short* FDb  = FSb  + (size_t)SC * 262144;
    unsigned short* G1b  = FDb  + (size_t)SC * 262144;
    float*          LOG  = (float*)(G1b + (size_t)SC * 262144);
    unsigned short* FS2b = (unsigned short*)((char*)LOG + (size_t)SC * 65536);
    unsigned short* FD2b = FS2b + (size_t)SC * 65536;
    float*          G2   = (float*)(FD2b + (size_t)SC * 65536);
    unsigned short* Ybf  = (unsigned short*)((char*)G2 + (size_t)SC * 262144);

    preprocess_k<<<4096, 256, 0, stream>>>(x, H, Hbf);
    castw_k<<<1094, 256, 0, stream>>>(W1s, W1d, W2s, W2d, Wfc, b1s, b1d, b2s, b2d,
                                      T1sd, T2sd, Tfc, bc1, bc2);
    csr_init_k<<<1, 512, 0, stream>>>(counts, fill);
    csr_hist_k<<<NE / 256, 256, 0, stream>>>(dst, counts);
    csr_scan_k<<<1, 64, 0, stream>>>(counts, row_ptr);
    csr_scatter_k<<<NE / 256, 256, 0, stream>>>(dst, row_ptr, fill, eidx);

    for (int s0 = 0; s0 < SEQL; s0 += SC) {
        const unsigned short* Hc = Hbf + (size_t)s0 * NN * DIN;
        int M = SC * NN;
        gemm_k<2><<<dim3(8, SC * 4), 256, 0, stream>>>(Hc, T1sd, bc1, FSb, FDb, M, 1024, 128, 0, 512);
        edge_logits1_k<<<SC * 1024, 256, 0, stream>>>(FSb, FDb, src, dst, attn1, LOG, SC);
        node_agg1_k<<<SC * 128, 256, 0, stream>>>(FSb, LOG, src, row_ptr, eidx, G1b, SC);
        gemm_k<2><<<dim3(2, SC * 4), 256, 0, stream>>>(G1b, T2sd, bc2, FS2b, FD2b, M, 256, 512, 0, 128);
        edge_logits2_k<<<SC * 1024, 256, 0, stream>>>(FS2b, FD2b, src, dst, attn2, LOG, SC);
        node_agg2_k<<<SC * 128, 256, 0, stream>>>(FS2b, LOG, src, row_ptr, eidx, G2, SC);
        ln_k<<<SC * 512, 128, 0, stream>>>(H, G2, gamma, beta, Ybf, s0);
        gemm_k<1><<<dim3(1, SC * 4), 256, 0, stream>>>(Ybf, Tfc, bfc, out, nullptr, M, 128, 128, s0, 0);
    }
}

// Round 10
// 265.896 us; speedup vs baseline: 2.8024x; 1.2483x over previous
//
#include <hip/hip_runtime.h>
#include <cmath>

#define NN    512
#define SEQL  64
#define DIN   128
#define NH    4
#define NE    4096
#define DOUTN 128

typedef __attribute__((ext_vector_type(4))) float f32x4;
typedef __attribute__((ext_vector_type(8))) short bf16x8;

__device__ __forceinline__ float lrelu(float v) { return v >= 0.f ? v : 0.2f * v; }

__device__ __forceinline__ unsigned short f2bf(float f) {
    union { float f; unsigned u; } x; x.f = f;
    unsigned r = (x.u + 0x7FFFu + ((x.u >> 16) & 1u)) >> 16;
    return (unsigned short)r;
}
__device__ __forceinline__ float bf2f(unsigned short h) {
    union { unsigned u; float f; } x; x.u = ((unsigned)h) << 16;
    return x.f;
}

// ---------------- preprocess: x[N][S][D] -> H f32 [S][N][D] + Hbf bf16 [S][N][D]
__global__ __launch_bounds__(256) void preprocess_k(const float* __restrict__ x,
                                                    float* __restrict__ H,
                                                    unsigned short* __restrict__ Hbf) {
    int tid = blockIdx.x * 256 + threadIdx.x;       // over 1,048,576 (4 elems each)
    int base = tid * 4;
    int d0 = base & 127;
    int s  = (base >> 7) & 63;
    int n  = base >> 13;
    float4 v = *(const float4*)(x + base);
    if (d0 == 0) {
        v.y = log10f(v.y + 1.f); v.z = log10f(v.z + 1.f); v.w = log10f(v.w + 1.f);
    } else {
        v.x = log10f(v.x + 1.f); v.y = log10f(v.y + 1.f);
        v.z = log10f(v.z + 1.f); v.w = log10f(v.w + 1.f);
    }
    if (v.x != v.x) v.x = 0.f;
    if (v.y != v.y) v.y = 0.f;
    if (v.z != v.z) v.z = 0.f;
    if (v.w != v.w) v.w = 0.f;
    size_t off = ((size_t)s * NN + n) * DIN + d0;
    *(float4*)(H + off) = v;
    ushort4 b; b.x = f2bf(v.x); b.y = f2bf(v.y); b.z = f2bf(v.z); b.w = f2bf(v.w);
    *(ushort4*)(Hbf + off) = b;
}

// ---------------- weight cast + transpose + concat: T1sd[1024][128], T2sd[256][512], Tfc[128][128]
__global__ __launch_bounds__(256) void castw_k(const float* __restrict__ W1s, const float* __restrict__ W1d,
                                               const float* __restrict__ W2s, const float* __restrict__ W2d,
                                               const float* __restrict__ Wfc,
                                               const float* __restrict__ b1s, const float* __restrict__ b1d,
                                               const float* __restrict__ b2s, const float* __restrict__ b2d,
                                               unsigned short* __restrict__ T1sd, unsigned short* __restrict__ T2sd,
                                               unsigned short* __restrict__ Tfc,
                                               float* __restrict__ bc1, float* __restrict__ bc2) {
    int i = blockIdx.x * 256 + threadIdx.x;          // 279,808 total
    if (i < 131072) {                                 // T1sd[1024][128]
        int n = i >> 7, k = i & 127;
        T1sd[i] = f2bf(n < 512 ? W1s[k * 512 + n] : W1d[k * 512 + (n - 512)]);
    } else if (i < 262144) {                          // T2sd[256][512]
        int j = i - 131072; int n = j >> 9, k = j & 511;
        T2sd[j] = f2bf(n < 128 ? W2s[k * 128 + n] : W2d[k * 128 + (n - 128)]);
    } else if (i < 278528) {                          // Tfc[128][128]
        int j = i - 262144; int n = j >> 7, k = j & 127;
        Tfc[j] = f2bf(Wfc[k * 128 + n]);
    } else if (i < 279552) {                          // bc1[1024]
        int j = i - 278528;
        bc1[j] = j < 512 ? b1s[j] : b1d[j - 512];
    } else if (i < 279808) {                          // bc2[256]
        int j = i - 279552;
        bc2[j] = j < 128 ? b2s[j] : b2d[j - 128];
    }
}

// ---------------- CSR build
__global__ void csr_init_k(int* counts, int* fill) {
    int t = threadIdx.x;
    counts[t] = 0; fill[t] = 0;
}
__global__ void csr_hist_k(const int* __restrict__ dst, int* counts) {
    int e = blockIdx.x * 256 + threadIdx.x;
    if (e < NE) atomicAdd(&counts[dst[e]], 1);
}
__global__ void csr_scan_k(const int* __restrict__ counts, int* __restrict__ row_ptr) {
    int l = threadIdx.x;                              // 64 lanes
    int c[8]; int lsum = 0;
#pragma unroll
    for (int j = 0; j < 8; ++j) { c[j] = counts[l * 8 + j]; lsum += c[j]; }
    int pre = lsum;
    for (int o = 1; o < 64; o <<= 1) {
        int v = __shfl_up(pre, o);
        if (l >= o) pre += v;
    }
    int acc = pre - lsum;                             // exclusive
#pragma unroll
    for (int j = 0; j < 8; ++j) { row_ptr[l * 8 + j] = acc; acc += c[j]; }
    if (l == 63) row_ptr[512] = acc;
}
__global__ void csr_scatter_k(const int* __restrict__ dst, const int* __restrict__ row_ptr,
                              int* fill, int* eidx) {
    int e = blockIdx.x * 256 + threadIdx.x;
    if (e < NE) {
        int dn = dst[e];
        int pos = atomicAdd(&fill[dn], 1);
        eidx[row_ptr[dn] + pos] = e;
    }
}

// ---------------- bf16 MFMA GEMM: C = A[M,K] @ BT[N,K]^T + bias
// MODE 0: single bf16 out (C1). MODE 1: f32 remap out (final FC). MODE 2: split bf16 (C1|C2 at half).
template<int MODE>
__global__ __launch_bounds__(256) void gemm_k(const unsigned short* __restrict__ A,
                                              const unsigned short* __restrict__ BT,
                                              const float* __restrict__ bias,
                                              void* __restrict__ C1v, void* __restrict__ C2v,
                                              int M, int N, int K, int s0, int half) {
    __shared__ unsigned short As[8192];   // 128 rows x 64 cols (phys-swizzled), 16 KB
    __shared__ unsigned short Bs[8192];
    int t = threadIdx.x;
    int w = t >> 6, l = t & 63;
    int wr = w >> 1, wc = w & 1;
    int m0 = blockIdx.y * 128, n0 = blockIdx.x * 128;

    f32x4 acc[4][4];
#pragma unroll
    for (int i = 0; i < 4; ++i)
#pragma unroll
        for (int j = 0; j < 4; ++j) acc[i][j] = (f32x4){0.f, 0.f, 0.f, 0.f};

    for (int k0 = 0; k0 < K; k0 += 64) {
        bf16x8 ra[4], rb[4];
#pragma unroll
        for (int r = 0; r < 4; ++r) {
            int q = t * 16 + r * 4096;                 // logical byte in 16 KB tile
            int row = q >> 7;                          // 0..127
            int cole = (q & 127) >> 1;                 // element col (8-aligned)
            ra[r] = *(const bf16x8*)(A  + (size_t)(m0 + row) * K + k0 + cole);
            rb[r] = *(const bf16x8*)(BT + (size_t)(n0 + row) * K + k0 + cole);
        }
        __syncthreads();                               // previous compute done
#pragma unroll
        for (int r = 0; r < 4; ++r) {
            int q = t * 16 + r * 4096;
            int row = q >> 7;
            int phys = (row << 7) | ((q & 127) ^ ((row & 7) << 4));
            *(bf16x8*)((char*)As + phys) = ra[r];
            *(bf16x8*)((char*)Bs + phys) = rb[r];
        }
        __syncthreads();
#pragma unroll
        for (int ks = 0; ks < 2; ++ks) {
            bf16x8 af[4], bfr[4];
#pragma unroll
            for (int i = 0; i < 4; ++i) {
                int row = wr * 64 + i * 16 + (l & 15);
                int colb = (ks * 64 + ((l >> 4) * 16)) ^ ((row & 7) << 4);
                af[i] = *(const bf16x8*)((const char*)As + (row << 7) + colb);
            }
#pragma unroll
            for (int j = 0; j < 4; ++j) {
                int row = wc * 64 + j * 16 + (l & 15);
                int colb = (ks * 64 + ((l >> 4) * 16)) ^ ((row & 7) << 4);
                bfr[j] = *(const bf16x8*)((const char*)Bs + (row << 7) + colb);
            }
#pragma unroll
            for (int i = 0; i < 4; ++i)
#pragma unroll
                for (int j = 0; j < 4; ++j)
                    acc[i][j] = __builtin_amdgcn_mfma_f32_16x16x32_bf16(af[i], bfr[j], acc[i][j], 0, 0, 0);
        }
    }

    float bl[4];
#pragma unroll
    for (int j = 0; j < 4; ++j) bl[j] = bias[n0 + wc * 64 + j * 16 + (l & 15)];
#pragma unroll
    for (int i = 0; i < 4; ++i) {
#pragma unroll
        for (int j = 0; j < 4; ++j) {
            int n = n0 + wc * 64 + j * 16 + (l & 15);
#pragma unroll
            for (int jj = 0; jj < 4; ++jj) {
                int m = m0 + wr * 64 + i * 16 + (l >> 4) * 4 + jj;
                float v = acc[i][j][jj] + bl[j];
                if (MODE == 1) {
                    int sl = m >> 9, node = m & 511;
                    ((float*)C1v)[((size_t)node * SEQL + (s0 + sl)) * DOUTN + n] = v;
                } else if (MODE == 2) {
                    unsigned short* dp = (unsigned short*)(n < half ? C1v : C2v);
                    int nn = n < half ? n : n - half;
                    dp[(size_t)m * half + nn] = f2bf(v);
                } else {
                    ((unsigned short*)C1v)[(size_t)m * N + n] = f2bf(v);
                }
            }
        }
    }
}

// ---------------- XCD-affine (s, idx) decode: B blocks per s, s%8 pinned to one XCD
__device__ __forceinline__ void s_swizzle(int bid, int sc, int B, int logB, int& s, int& idx) {
    if ((sc & 7) == 0) {
        int xcd = bid & 7;
        int j = bid >> 3;
        int grp = j >> logB;
        idx = j & (B - 1);
        s = grp * 8 + xcd;
    } else {
        s = bid >> logB;
        idx = bid & (B - 1);
    }
}

// ---------------- FUSED layer-1: edge logits + online softmax + aggregation.
// One wave per (s,n). lane l: head h=l>>4, feats h*128 + (l&15)*8 .. +8.
// FD row + attn loaded ONCE per node; per edge: one 1KB FS gather -> logit (4-shfl
// 16-lane reduce) -> online-softmax accumulate reusing the in-register FS values.
__global__ __launch_bounds__(256) void fused_l1_k(const unsigned short* __restrict__ FS,
                                                  const unsigned short* __restrict__ FD,
                                                  const int* __restrict__ src,
                                                  const int* __restrict__ row_ptr,
                                                  const int* __restrict__ eidx,
                                                  const float* __restrict__ attn,
                                                  unsigned short* __restrict__ G1,
                                                  int sc) {
    int wv = threadIdx.x >> 6, l = threadIdx.x & 63;
    int s, nb;
    s_swizzle(blockIdx.x, sc, 128, 7, s, nb);
    int n = nb * 4 + wv;
    int e0 = row_ptr[n], e1 = row_ptr[n + 1];
    float at[8], fdv[8];
    bf16x8 fdr = *(const bf16x8*)(FD + ((size_t)s * NN + n) * 512 + l * 8);
#pragma unroll
    for (int k = 0; k < 8; ++k) { at[k] = attn[l * 8 + k]; fdv[k] = bf2f((unsigned short)fdr[k]); }
    const unsigned short* fsbase = FS + (size_t)s * NN * 512 + l * 8;
    float m_run = -INFINITY, den = 0.f;
    float acc[8] = {};
    for (int j = e0; j < e1; ++j) {
        int e = eidx[j];
        bf16x8 raw = *(const bf16x8*)(fsbase + (size_t)src[e] * 512);
        float fv[8], part = 0.f;
#pragma unroll
        for (int k = 0; k < 8; ++k) {
            fv[k] = bf2f((unsigned short)raw[k]);
            part += at[k] * lrelu(fv[k] + fdv[k]);
        }
        part += __shfl_xor(part, 1);
        part += __shfl_xor(part, 2);
        part += __shfl_xor(part, 4);
        part += __shfl_xor(part, 8);       // logit, uniform within 16-lane head group
        if (part > m_run) {
            float sc_ = expf(m_run - part); // first edge: exp(-inf)=0
            den = den * sc_ + 1.f;
#pragma unroll
            for (int k = 0; k < 8; ++k) acc[k] = acc[k] * sc_ + fv[k];
            m_run = part;
        } else {
            float w = expf(part - m_run);
            den += w;
#pragma unroll
            for (int k = 0; k < 8; ++k) acc[k] += w * fv[k];
        }
    }
    float inv = 1.f / den;
    bf16x8 o8;
#pragma unroll
    for (int k = 0; k < 8; ++k) o8[k] = (short)f2bf(acc[k] * inv);
    *(bf16x8*)(G1 + ((size_t)s * NN + n) * 512 + l * 8) = o8;
}

// ---------------- FUSED layer-2: edge logits + online softmax + agg + residual + LN.
// One wave per (s,n). lane l: feats {2l, 2l+1}. Writes Ybf directly (G2/ln_k eliminated).
__global__ __launch_bounds__(256) void fused_l2_k(const unsigned short* __restrict__ FS,
                                                  const unsigned short* __restrict__ FD,
                                                  const int* __restrict__ src,
                                                  const int* __restrict__ row_ptr,
                                                  const int* __restrict__ eidx,
                                                  const float* __restrict__ attn,
                                                  const float* __restrict__ H,
                                                  const float* __restrict__ gamma,
                                                  const float* __restrict__ beta,
                                                  unsigned short* __restrict__ Y,
                                                  int s0, int sc) {
    int wv = threadIdx.x >> 6, l = threadIdx.x & 63;
    int s, nb;
    s_swizzle(blockIdx.x, sc, 128, 7, s, nb);
    int n = nb * 4 + wv;
    int e0 = row_ptr[n], e1 = row_ptr[n + 1];
    float a0 = attn[l * 2], a1 = attn[l * 2 + 1];
    ushort2 fdr = *(const ushort2*)(FD + ((size_t)s * NN + n) * 128 + l * 2);
    float fd0 = bf2f(fdr.x), fd1 = bf2f(fdr.y);
    const unsigned short* fb = FS + (size_t)s * NN * 128 + l * 2;
    float m_run = -INFINITY, den = 0.f, c0 = 0.f, c1 = 0.f;
    for (int j = e0; j < e1; ++j) {
        int e = eidx[j];
        ushort2 uv = *(const ushort2*)(fb + (size_t)src[e] * 128);
        float f0 = bf2f(uv.x), f1 = bf2f(uv.y);
        float part = a0 * lrelu(f0 + fd0) + a1 * lrelu(f1 + fd1);
#pragma unroll
        for (int o = 1; o < 64; o <<= 1) part += __shfl_xor(part, o);  // wave-wide logit
        if (part > m_run) {
            float sc_ = expf(m_run - part);
            den = den * sc_ + 1.f;
            c0 = c0 * sc_ + f0;
            c1 = c1 * sc_ + f1;
            m_run = part;
        } else {
            float w = expf(part - m_run);
            den += w;
            c0 += w * f0;
            c1 += w * f1;
        }
    }
    float inv = 1.f / den;
    float g0 = c0 * inv, g1 = c1 * inv;
    float2 xp = *(const float2*)(H + ((size_t)(s0 + s) * NN + n) * DIN + l * 2);
    if (g0 != g0) g0 = xp.x;
    if (g1 != g1) g1 = xp.y;
    float o0 = xp.x + g0, o1 = xp.y + g1;
    float ssum = o0 + o1, ssq = o0 * o0 + o1 * o1;
#pragma unroll
    for (int o = 32; o > 0; o >>= 1) { ssum += __shfl_xor(ssum, o); ssq += __shfl_xor(ssq, o); }
    float mu  = ssum * (1.f / 128.f);
    float var = ssq * (1.f / 128.f) - mu * mu;
    float rstd = rsqrtf(var + 1e-5f);
    float y0 = (o0 - mu) * rstd * gamma[l * 2]     + beta[l * 2];
    float y1 = (o1 - mu) * rstd * gamma[l * 2 + 1] + beta[l * 2 + 1];
    ushort2 yo; yo.x = f2bf(y0); yo.y = f2bf(y1);
    *(ushort2*)(Y + ((size_t)s * NN + n) * 128 + l * 2) = yo;
}

extern "C" void kernel_launch(void* const* d_in, const int* in_sizes, int n_in,
                              void* d_out, int out_size, void* d_ws, size_t ws_size,
                              hipStream_t stream) {
    const float* x     = (const float*)d_in[0];
    const int*   src   = (const int*)d_in[1];
    const int*   dst   = (const int*)d_in[2];
    const float* W1s   = (const float*)d_in[3];
    const float* b1s   = (const float*)d_in[4];
    const float* W1d   = (const float*)d_in[5];
    const float* b1d   = (const float*)d_in[6];
    const float* attn1 = (const float*)d_in[7];
    const float* W2s   = (const float*)d_in[8];
    const float* b2s   = (const float*)d_in[9];
    const float* W2d   = (const float*)d_in[10];
    const float* b2d   = (const float*)d_in[11];
    const float* attn2 = (const float*)d_in[12];
    const float* gamma = (const float*)d_in[13];
    const float* beta  = (const float*)d_in[14];
    const float* Wfc   = (const float*)d_in[15];
    const float* bfc   = (const float*)d_in[16];
    float* out = (float*)d_out;

    char* p = (char*)d_ws;
    float*          H    = (float*)p;                          // 16,777,216 B
    unsigned short* Hbf  = (unsigned short*)(p + 16777216);    //  8,388,608 B
    unsigned short* T1sd = (unsigned short*)(p + 25165824);    //    262,144 B
    unsigned short* T2sd = (unsigned short*)(p + 25427968);    //    262,144 B
    unsigned short* Tfc  = (unsigned short*)(p + 25690112);    //     32,768 B
    float*          bc1  = (float*)(p + 25722880);             //      4,096 B
    float*          bc2  = (float*)(p + 25726976);             //      1,024 B
    int* counts  = (int*)(p + 25728000);
    int* row_ptr = counts + 512;
    int* fill    = row_ptr + 513;
    int* eidx    = fill + 512;                                 // ends 25,750,532
    const size_t base = 25755648;

    // per-seq-chunk bytes: 3*524288 + 3*131072 = 1,966,080
    int SC = 1;
    const int cand[7] = {64, 32, 16, 8, 4, 2, 1};
    for (int i = 0; i < 7; ++i)
        if (base + (size_t)cand[i] * 1966080ull <= ws_size) { SC = cand[i]; break; }

    unsigned short* FSb  = (unsigned short*)(p + base);
    unsigned short* FDb  = FSb  + (size_t)SC * 262144;
    unsigned short* G1b  = FDb  + (size_t)SC * 262144;
    unsigned short* FS2b = G1b  + (size_t)SC * 262144;
    unsigned short* FD2b = FS2b + (size_t)SC * 65536;
    unsigned short* Ybf  = FD2b + (size_t)SC * 65536;

    preprocess_k<<<4096, 256, 0, stream>>>(x, H, Hbf);
    castw_k<<<1094, 256, 0, stream>>>(W1s, W1d, W2s, W2d, Wfc, b1s, b1d, b2s, b2d,
                                      T1sd, T2sd, Tfc, bc1, bc2);
    csr_init_k<<<1, 512, 0, stream>>>(counts, fill);
    csr_hist_k<<<NE / 256, 256, 0, stream>>>(dst, counts);
    csr_scan_k<<<1, 64, 0, stream>>>(counts, row_ptr);
    csr_scatter_k<<<NE / 256, 256, 0, stream>>>(dst, row_ptr, fill, eidx);

    for (int s0 = 0; s0 < SEQL; s0 += SC) {
        const unsigned short* Hc = Hbf + (size_t)s0 * NN * DIN;
        int M = SC * NN;
        gemm_k<2><<<dim3(8, SC * 4), 256, 0, stream>>>(Hc, T1sd, bc1, FSb, FDb, M, 1024, 128, 0, 512);
        fused_l1_k<<<SC * 128, 256, 0, stream>>>(FSb, FDb, src, row_ptr, eidx, attn1, G1b, SC);
        gemm_k<2><<<dim3(2, SC * 4), 256, 0, stream>>>(G1b, T2sd, bc2, FS2b, FD2b, M, 256, 512, 0, 128);
        fused_l2_k<<<SC * 128, 256, 0, stream>>>(FS2b, FD2b, src, row_ptr, eidx, attn2,
                                                 H, gamma, beta, Ybf, s0, SC);
        gemm_k<1><<<dim3(1, SC * 4), 256, 0, stream>>>(Ybf, Tfc, bfc, out, nullptr, M, 128, 128, s0, 0);
    }
}

// Round 11
// 247.917 us; speedup vs baseline: 3.0056x; 1.0725x over previous
//
#include <hip/hip_runtime.h>
#include <cmath>

#define NN    512
#define SEQL  64
#define DIN   128
#define NH    4
#define NE    4096
#define DOUTN 128
#define LOG2E 1.44269504088896340736f

typedef __attribute__((ext_vector_type(4))) float f32x4;
typedef __attribute__((ext_vector_type(8))) short bf16x8;

__device__ __forceinline__ float lrelu(float v) { return v >= 0.f ? v : 0.2f * v; }

__device__ __forceinline__ unsigned short f2bf(float f) {
    union { float f; unsigned u; } x; x.f = f;
    unsigned r = (x.u + 0x7FFFu + ((x.u >> 16) & 1u)) >> 16;
    return (unsigned short)r;
}
__device__ __forceinline__ float bf2f(unsigned short h) {
    union { unsigned u; float f; } x; x.u = ((unsigned)h) << 16;
    return x.f;
}

// ---------------- preprocess: x[N][S][D] -> H f32 [S][N][D] + Hbf bf16 [S][N][D]
__global__ __launch_bounds__(256) void preprocess_k(const float* __restrict__ x,
                                                    float* __restrict__ H,
                                                    unsigned short* __restrict__ Hbf) {
    int tid = blockIdx.x * 256 + threadIdx.x;       // over 1,048,576 (4 elems each)
    int base = tid * 4;
    int d0 = base & 127;
    int s  = (base >> 7) & 63;
    int n  = base >> 13;
    float4 v = *(const float4*)(x + base);
    if (d0 == 0) {
        v.y = log10f(v.y + 1.f); v.z = log10f(v.z + 1.f); v.w = log10f(v.w + 1.f);
    } else {
        v.x = log10f(v.x + 1.f); v.y = log10f(v.y + 1.f);
        v.z = log10f(v.z + 1.f); v.w = log10f(v.w + 1.f);
    }
    if (v.x != v.x) v.x = 0.f;
    if (v.y != v.y) v.y = 0.f;
    if (v.z != v.z) v.z = 0.f;
    if (v.w != v.w) v.w = 0.f;
    size_t off = ((size_t)s * NN + n) * DIN + d0;
    *(float4*)(H + off) = v;
    ushort4 b; b.x = f2bf(v.x); b.y = f2bf(v.y); b.z = f2bf(v.z); b.w = f2bf(v.w);
    *(ushort4*)(Hbf + off) = b;
}

// ---------------- weight cast + transpose + concat: T1sd[1024][128], T2sd[256][512], Tfc[128][128]
__global__ __launch_bounds__(256) void castw_k(const float* __restrict__ W1s, const float* __restrict__ W1d,
                                               const float* __restrict__ W2s, const float* __restrict__ W2d,
                                               const float* __restrict__ Wfc,
                                               const float* __restrict__ b1s, const float* __restrict__ b1d,
                                               const float* __restrict__ b2s, const float* __restrict__ b2d,
                                               unsigned short* __restrict__ T1sd, unsigned short* __restrict__ T2sd,
                                               unsigned short* __restrict__ Tfc,
                                               float* __restrict__ bc1, float* __restrict__ bc2) {
    int i = blockIdx.x * 256 + threadIdx.x;          // 279,808 total
    if (i < 131072) {                                 // T1sd[1024][128]
        int n = i >> 7, k = i & 127;
        T1sd[i] = f2bf(n < 512 ? W1s[k * 512 + n] : W1d[k * 512 + (n - 512)]);
    } else if (i < 262144) {                          // T2sd[256][512]
        int j = i - 131072; int n = j >> 9, k = j & 511;
        T2sd[j] = f2bf(n < 128 ? W2s[k * 128 + n] : W2d[k * 128 + (n - 128)]);
    } else if (i < 278528) {                          // Tfc[128][128]
        int j = i - 262144; int n = j >> 7, k = j & 127;
        Tfc[j] = f2bf(Wfc[k * 128 + n]);
    } else if (i < 279552) {                          // bc1[1024]
        int j = i - 278528;
        bc1[j] = j < 512 ? b1s[j] : b1d[j - 512];
    } else if (i < 279808) {                          // bc2[256]
        int j = i - 279552;
        bc2[j] = j < 128 ? b2s[j] : b2d[j - 128];
    }
}

// ---------------- CSR build (stores SRC NODE IDS in CSR order — fused kernels need no edge ids)
__global__ void csr_init_k(int* counts, int* fill) {
    int t = threadIdx.x;
    counts[t] = 0; fill[t] = 0;
}
__global__ void csr_hist_k(const int* __restrict__ dst, int* counts) {
    int e = blockIdx.x * 256 + threadIdx.x;
    if (e < NE) atomicAdd(&counts[dst[e]], 1);
}
__global__ void csr_scan_k(const int* __restrict__ counts, int* __restrict__ row_ptr) {
    int l = threadIdx.x;                              // 64 lanes
    int c[8]; int lsum = 0;
#pragma unroll
    for (int j = 0; j < 8; ++j) { c[j] = counts[l * 8 + j]; lsum += c[j]; }
    int pre = lsum;
    for (int o = 1; o < 64; o <<= 1) {
        int v = __shfl_up(pre, o);
        if (l >= o) pre += v;
    }
    int acc = pre - lsum;                             // exclusive
#pragma unroll
    for (int j = 0; j < 8; ++j) { row_ptr[l * 8 + j] = acc; acc += c[j]; }
    if (l == 63) row_ptr[512] = acc;
}
__global__ void csr_scatter_k(const int* __restrict__ src, const int* __restrict__ dst,
                              const int* __restrict__ row_ptr, int* fill, int* esrc) {
    int e = blockIdx.x * 256 + threadIdx.x;
    if (e < NE) {
        int dn = dst[e];
        int pos = atomicAdd(&fill[dn], 1);
        esrc[row_ptr[dn] + pos] = src[e];             // store src node id directly
    }
}

// ---------------- bf16 MFMA GEMM: C = A[M,K] @ BT[N,K]^T + bias
// MODE 0: single bf16 out (C1). MODE 1: f32 remap out (final FC). MODE 2: split bf16 (C1|C2 at half).
template<int MODE>
__global__ __launch_bounds__(256) void gemm_k(const unsigned short* __restrict__ A,
                                              const unsigned short* __restrict__ BT,
                                              const float* __restrict__ bias,
                                              void* __restrict__ C1v, void* __restrict__ C2v,
                                              int M, int N, int K, int s0, int half) {
    __shared__ unsigned short As[8192];   // 128 rows x 64 cols (phys-swizzled), 16 KB
    __shared__ unsigned short Bs[8192];
    int t = threadIdx.x;
    int w = t >> 6, l = t & 63;
    int wr = w >> 1, wc = w & 1;
    int m0 = blockIdx.y * 128, n0 = blockIdx.x * 128;

    f32x4 acc[4][4];
#pragma unroll
    for (int i = 0; i < 4; ++i)
#pragma unroll
        for (int j = 0; j < 4; ++j) acc[i][j] = (f32x4){0.f, 0.f, 0.f, 0.f};

    for (int k0 = 0; k0 < K; k0 += 64) {
        bf16x8 ra[4], rb[4];
#pragma unroll
        for (int r = 0; r < 4; ++r) {
            int q = t * 16 + r * 4096;                 // logical byte in 16 KB tile
            int row = q >> 7;                          // 0..127
            int cole = (q & 127) >> 1;                 // element col (8-aligned)
            ra[r] = *(const bf16x8*)(A  + (size_t)(m0 + row) * K + k0 + cole);
            rb[r] = *(const bf16x8*)(BT + (size_t)(n0 + row) * K + k0 + cole);
        }
        __syncthreads();                               // previous compute done
#pragma unroll
        for (int r = 0; r < 4; ++r) {
            int q = t * 16 + r * 4096;
            int row = q >> 7;
            int phys = (row << 7) | ((q & 127) ^ ((row & 7) << 4));
            *(bf16x8*)((char*)As + phys) = ra[r];
            *(bf16x8*)((char*)Bs + phys) = rb[r];
        }
        __syncthreads();
#pragma unroll
        for (int ks = 0; ks < 2; ++ks) {
            bf16x8 af[4], bfr[4];
#pragma unroll
            for (int i = 0; i < 4; ++i) {
                int row = wr * 64 + i * 16 + (l & 15);
                int colb = (ks * 64 + ((l >> 4) * 16)) ^ ((row & 7) << 4);
                af[i] = *(const bf16x8*)((const char*)As + (row << 7) + colb);
            }
#pragma unroll
            for (int j = 0; j < 4; ++j) {
                int row = wc * 64 + j * 16 + (l & 15);
                int colb = (ks * 64 + ((l >> 4) * 16)) ^ ((row & 7) << 4);
                bfr[j] = *(const bf16x8*)((const char*)Bs + (row << 7) + colb);
            }
#pragma unroll
            for (int i = 0; i < 4; ++i)
#pragma unroll
                for (int j = 0; j < 4; ++j)
                    acc[i][j] = __builtin_amdgcn_mfma_f32_16x16x32_bf16(af[i], bfr[j], acc[i][j], 0, 0, 0);
        }
    }

    float bl[4];
#pragma unroll
    for (int j = 0; j < 4; ++j) bl[j] = bias[n0 + wc * 64 + j * 16 + (l & 15)];
#pragma unroll
    for (int i = 0; i < 4; ++i) {
#pragma unroll
        for (int j = 0; j < 4; ++j) {
            int n = n0 + wc * 64 + j * 16 + (l & 15);
#pragma unroll
            for (int jj = 0; jj < 4; ++jj) {
                int m = m0 + wr * 64 + i * 16 + (l >> 4) * 4 + jj;
                float v = acc[i][j][jj] + bl[j];
                if (MODE == 1) {
                    int sl = m >> 9, node = m & 511;
                    ((float*)C1v)[((size_t)node * SEQL + (s0 + sl)) * DOUTN + n] = v;
                } else if (MODE == 2) {
                    unsigned short* dp = (unsigned short*)(n < half ? C1v : C2v);
                    int nn = n < half ? n : n - half;
                    dp[(size_t)m * half + nn] = f2bf(v);
                } else {
                    ((unsigned short*)C1v)[(size_t)m * N + n] = f2bf(v);
                }
            }
        }
    }
}

// ---------------- XCD-affine (s, idx) decode: B blocks per s, s%8 pinned to one XCD
__device__ __forceinline__ void s_swizzle(int bid, int sc, int B, int logB, int& s, int& idx) {
    if ((sc & 7) == 0) {
        int xcd = bid & 7;
        int j = bid >> 3;
        int grp = j >> logB;
        idx = j & (B - 1);
        s = grp * 8 + xcd;
    } else {
        s = bid >> logB;
        idx = bid & (B - 1);
    }
}

// ---------------- FUSED layer-1: logits + online softmax + agg. One wave per (s,n).
// Batch-4 gather pipeline (4 FS loads in flight), src-id CSR (no edge indirection),
// exp2-softmax (attn pre-scaled by log2e in-register).
__global__ __launch_bounds__(256) void fused_l1_k(const unsigned short* __restrict__ FS,
                                                  const unsigned short* __restrict__ FD,
                                                  const int* __restrict__ row_ptr,
                                                  const int* __restrict__ esrc,
                                                  const float* __restrict__ attn,
                                                  unsigned short* __restrict__ G1,
                                                  int sc) {
    int wv = threadIdx.x >> 6, l = threadIdx.x & 63;
    int s, nb;
    s_swizzle(blockIdx.x, sc, 128, 7, s, nb);
    int n = nb * 4 + wv;
    int e0 = row_ptr[n], e1 = row_ptr[n + 1];
    float at[8], fdv[8];
    bf16x8 fdr = *(const bf16x8*)(FD + ((size_t)s * NN + n) * 512 + l * 8);
#pragma unroll
    for (int k = 0; k < 8; ++k) {
        at[k] = attn[l * 8 + k] * LOG2E;
        fdv[k] = bf2f((unsigned short)fdr[k]);
    }
    const unsigned short* fsbase = FS + (size_t)s * NN * 512 + l * 8;
    float m_run = -INFINITY, den = 0.f;
    float acc[8] = {};

    auto process = [&](bf16x8 raw) {
        float fv[8], part = 0.f;
#pragma unroll
        for (int k = 0; k < 8; ++k) {
            fv[k] = bf2f((unsigned short)raw[k]);
            part += at[k] * lrelu(fv[k] + fdv[k]);
        }
        part += __shfl_xor(part, 1);
        part += __shfl_xor(part, 2);
        part += __shfl_xor(part, 4);
        part += __shfl_xor(part, 8);       // scaled logit, uniform within 16-lane head group
        if (part > m_run) {
            float sc_ = exp2f(m_run - part);
            den = den * sc_ + 1.f;
#pragma unroll
            for (int k = 0; k < 8; ++k) acc[k] = acc[k] * sc_ + fv[k];
            m_run = part;
        } else {
            float w = exp2f(part - m_run);
            den += w;
#pragma unroll
            for (int k = 0; k < 8; ++k) acc[k] += w * fv[k];
        }
    };

    for (int j = e0; j < e1; j += 4) {     // bounds wave-uniform: no divergence
        int rem = e1 - j;
        bf16x8 r0, r1, r2, r3;
        r0 = *(const bf16x8*)(fsbase + (size_t)esrc[j] * 512);
        if (rem > 1) r1 = *(const bf16x8*)(fsbase + (size_t)esrc[j + 1] * 512);
        if (rem > 2) r2 = *(const bf16x8*)(fsbase + (size_t)esrc[j + 2] * 512);
        if (rem > 3) r3 = *(const bf16x8*)(fsbase + (size_t)esrc[j + 3] * 512);
        process(r0);
        if (rem > 1) process(r1);
        if (rem > 2) process(r2);
        if (rem > 3) process(r3);
    }
    float inv = 1.f / den;
    bf16x8 o8;
#pragma unroll
    for (int k = 0; k < 8; ++k) o8[k] = (short)f2bf(acc[k] * inv);
    *(bf16x8*)(G1 + ((size_t)s * NN + n) * 512 + l * 8) = o8;
}

// ---------------- FUSED layer-2: logits + online softmax + agg + residual + LN.
// One wave per (s,n); batch-4 pipeline; exp2-softmax; writes Ybf directly.
__global__ __launch_bounds__(256) void fused_l2_k(const unsigned short* __restrict__ FS,
                                                  const unsigned short* __restrict__ FD,
                                                  const int* __restrict__ row_ptr,
                                                  const int* __restrict__ esrc,
                                                  const float* __restrict__ attn,
                                                  const float* __restrict__ H,
                                                  const float* __restrict__ gamma,
                                                  const float* __restrict__ beta,
                                                  unsigned short* __restrict__ Y,
                                                  int s0, int sc) {
    int wv = threadIdx.x >> 6, l = threadIdx.x & 63;
    int s, nb;
    s_swizzle(blockIdx.x, sc, 128, 7, s, nb);
    int n = nb * 4 + wv;
    int e0 = row_ptr[n], e1 = row_ptr[n + 1];
    float a0 = attn[l * 2] * LOG2E, a1 = attn[l * 2 + 1] * LOG2E;
    ushort2 fdr = *(const ushort2*)(FD + ((size_t)s * NN + n) * 128 + l * 2);
    float fd0 = bf2f(fdr.x), fd1 = bf2f(fdr.y);
    const unsigned short* fb = FS + (size_t)s * NN * 128 + l * 2;
    float m_run = -INFINITY, den = 0.f, c0 = 0.f, c1 = 0.f;

    auto process = [&](ushort2 uv) {
        float f0 = bf2f(uv.x), f1 = bf2f(uv.y);
        float part = a0 * lrelu(f0 + fd0) + a1 * lrelu(f1 + fd1);
#pragma unroll
        for (int o = 1; o < 64; o <<= 1) part += __shfl_xor(part, o);  // wave-wide scaled logit
        if (part > m_run) {
            float sc_ = exp2f(m_run - part);
            den = den * sc_ + 1.f;
            c0 = c0 * sc_ + f0;
            c1 = c1 * sc_ + f1;
            m_run = part;
        } else {
            float w = exp2f(part - m_run);
            den += w;
            c0 += w * f0;
            c1 += w * f1;
        }
    };

    for (int j = e0; j < e1; j += 4) {
        int rem = e1 - j;
        ushort2 u0, u1, u2, u3;
        u0 = *(const ushort2*)(fb + (size_t)esrc[j] * 128);
        if (rem > 1) u1 = *(const ushort2*)(fb + (size_t)esrc[j + 1] * 128);
        if (rem > 2) u2 = *(const ushort2*)(fb + (size_t)esrc[j + 2] * 128);
        if (rem > 3) u3 = *(const ushort2*)(fb + (size_t)esrc[j + 3] * 128);
        process(u0);
        if (rem > 1) process(u1);
        if (rem > 2) process(u2);
        if (rem > 3) process(u3);
    }
    float inv = 1.f / den;
    float g0 = c0 * inv, g1 = c1 * inv;
    float2 xp = *(const float2*)(H + ((size_t)(s0 + s) * NN + n) * DIN + l * 2);
    if (g0 != g0) g0 = xp.x;
    if (g1 != g1) g1 = xp.y;
    float o0 = xp.x + g0, o1 = xp.y + g1;
    float ssum = o0 + o1, ssq = o0 * o0 + o1 * o1;
#pragma unroll
    for (int o = 32; o > 0; o >>= 1) { ssum += __shfl_xor(ssum, o); ssq += __shfl_xor(ssq, o); }
    float mu  = ssum * (1.f / 128.f);
    float var = ssq * (1.f / 128.f) - mu * mu;
    float rstd = rsqrtf(var + 1e-5f);
    float y0 = (o0 - mu) * rstd * gamma[l * 2]     + beta[l * 2];
    float y1 = (o1 - mu) * rstd * gamma[l * 2 + 1] + beta[l * 2 + 1];
    ushort2 yo; yo.x = f2bf(y0); yo.y = f2bf(y1);
    *(ushort2*)(Y + ((size_t)s * NN + n) * 128 + l * 2) = yo;
}

extern "C" void kernel_launch(void* const* d_in, const int* in_sizes, int n_in,
                              void* d_out, int out_size, void* d_ws, size_t ws_size,
                              hipStream_t stream) {
    const float* x     = (const float*)d_in[0];
    const int*   src   = (const int*)d_in[1];
    const int*   dst   = (const int*)d_in[2];
    const float* W1s   = (const float*)d_in[3];
    const float* b1s   = (const float*)d_in[4];
    const float* W1d   = (const float*)d_in[5];
    const float* b1d   = (const float*)d_in[6];
    const float* attn1 = (const float*)d_in[7];
    const float* W2s   = (const float*)d_in[8];
    const float* b2s   = (const float*)d_in[9];
    const float* W2d   = (const float*)d_in[10];
    const float* b2d   = (const float*)d_in[11];
    const float* attn2 = (const float*)d_in[12];
    const float* gamma = (const float*)d_in[13];
    const float* beta  = (const float*)d_in[14];
    const float* Wfc   = (const float*)d_in[15];
    const float* bfc   = (const float*)d_in[16];
    float* out = (float*)d_out;

    char* p = (char*)d_ws;
    float*          H    = (float*)p;                          // 16,777,216 B
    unsigned short* Hbf  = (unsigned short*)(p + 16777216);    //  8,388,608 B
    unsigned short* T1sd = (unsigned short*)(p + 25165824);    //    262,144 B
    unsigned short* T2sd = (unsigned short*)(p + 25427968);    //    262,144 B
    unsigned short* Tfc  = (unsigned short*)(p + 25690112);    //     32,768 B
    float*          bc1  = (float*)(p + 25722880);             //      4,096 B
    float*          bc2  = (float*)(p + 25726976);             //      1,024 B
    int* counts  = (int*)(p + 25728000);
    int* row_ptr = counts + 512;
    int* fill    = row_ptr + 513;
    int* esrc    = fill + 512;                                 // ends 25,750,532
    const size_t base = 25755648;

    // per-seq-chunk bytes: 3*524288 + 3*131072 = 1,966,080
    int SC = 1;
    const int cand[7] = {64, 32, 16, 8, 4, 2, 1};
    for (int i = 0; i < 7; ++i)
        if (base + (size_t)cand[i] * 1966080ull <= ws_size) { SC = cand[i]; break; }

    unsigned short* FSb  = (unsigned short*)(p + base);
    unsigned short* FDb  = FSb  + (size_t)SC * 262144;
    unsigned short* G1b  = FDb  + (size_t)SC * 262144;
    unsigned short* FS2b = G1b  + (size_t)SC * 262144;
    unsigned short* FD2b = FS2b + (size_t)SC * 65536;
    unsigned short* Ybf  = FD2b + (size_t)SC * 65536;

    preprocess_k<<<4096, 256, 0, stream>>>(x, H, Hbf);
    castw_k<<<1094, 256, 0, stream>>>(W1s, W1d, W2s, W2d, Wfc, b1s, b1d, b2s, b2d,
                                      T1sd, T2sd, Tfc, bc1, bc2);
    csr_init_k<<<1, 512, 0, stream>>>(counts, fill);
    csr_hist_k<<<NE / 256, 256, 0, stream>>>(dst, counts);
    csr_scan_k<<<1, 64, 0, stream>>>(counts, row_ptr);
    csr_scatter_k<<<NE / 256, 256, 0, stream>>>(src, dst, row_ptr, fill, esrc);

    for (int s0 = 0; s0 < SEQL; s0 += SC) {
        const unsigned short* Hc = Hbf + (size_t)s0 * NN * DIN;
        int M = SC * NN;
        gemm_k<2><<<dim3(8, SC * 4), 256, 0, stream>>>(Hc, T1sd, bc1, FSb, FDb, M, 1024, 128, 0, 512);
        fused_l1_k<<<SC * 128, 256, 0, stream>>>(FSb, FDb, row_ptr, esrc, attn1, G1b, SC);
        gemm_k<2><<<dim3(2, SC * 4), 256, 0, stream>>>(G1b, T2sd, bc2, FS2b, FD2b, M, 256, 512, 0, 128);
        fused_l2_k<<<SC * 128, 256, 0, stream>>>(FS2b, FD2b, row_ptr, esrc, attn2,
                                                 H, gamma, beta, Ybf, s0, SC);
        gemm_k<1><<<dim3(1, SC * 4), 256, 0, stream>>>(Ybf, Tfc, bfc, out, nullptr, M, 128, 128, s0, 0);
    }
}